// Round 20
// baseline (1131.194 us; speedup 1.0000x reference)
//
#include <hip/hip_runtime.h>
#include <hip/hip_bf16.h>
#include <math.h>

typedef unsigned short ushort_t;
typedef __attribute__((ext_vector_type(8))) __bf16 bf16x8;
typedef __attribute__((ext_vector_type(4))) float f32x4;
typedef __attribute__((ext_vector_type(8))) short s8v;
typedef __attribute__((ext_vector_type(4))) short s4v;

#define SQ 2048
#define DM 1024
#define NH 16
#define HDIM 64
#define FFD 4096
#define NVOC 32000

__device__ inline float b2f(unsigned short u) {
  union { unsigned int i; float f; } x; x.i = ((unsigned int)u) << 16; return x.f;
}
__device__ inline unsigned short f2b(float f) {
  __hip_bfloat16 h = __float2bfloat16(f);
  return *reinterpret_cast<unsigned short*>(&h);
}
__device__ inline void split2(float x, ushort_t& h, ushort_t& l) {
  h = f2b(x);
  l = f2b(x - b2f(h));
}
__device__ inline float geluf(float v) {
  return 0.5f * v * (1.0f + erff(v * 0.70710678118654752f));
}
__device__ __forceinline__ void gld16(const void* g, void* l) {
  __builtin_amdgcn_global_load_lds(
      (const __attribute__((address_space(1))) void*)g,
      (__attribute__((address_space(3))) void*)l, 16, 0, 0);
}
#define MFMA __builtin_amdgcn_mfma_f32_16x16x32_bf16

// ---------------------------------------------------------------------------
// Split GEMM engine (pre-gate math), 2-phase double-buffered.
// EPI: 2 f32 partial store (kc*pC), 4 gelu+bias split-store,
//      5 split-store+bias with V-region (n0>=2048) written TRANSPOSED to TH/TL.
// ---------------------------------------------------------------------------
template<int EPI, int NT, int KS>
__device__ __forceinline__ void gemmsp_body(
    const ushort_t* __restrict__ AH, const ushort_t* __restrict__ AL,
    int lda, long long bA,
    const ushort_t* __restrict__ BH, const ushort_t* __restrict__ BL,
    int ldb, long long bB,
    float* __restrict__ C, ushort_t* __restrict__ CH, ushort_t* __restrict__ CL,
    int ldc, long long bC, long long pC,
    int M, int N, int K, const float* __restrict__ bias, float alpha,
    ushort_t* __restrict__ TH, ushort_t* __restrict__ TL)
{
  int z = blockIdx.z, h = z / KS, kc = z % KS;
  const ushort_t* AHp = AH + (long long)h * bA + (long long)kc * K;
  const ushort_t* ALp = AL + (long long)h * bA + (long long)kc * K;
  const ushort_t* BHp = BH + (long long)h * bB + (long long)kc * K;
  const ushort_t* BLp = BL + (long long)h * bB + (long long)kc * K;
  int m0 = blockIdx.x * 128, n0 = blockIdx.y * NT;
  const int NF = NT / 32;

  __shared__ __align__(16) ushort_t sAH[2][128 * 32], sAL[2][128 * 32];
  __shared__ __align__(16) ushort_t sBH[2][NT * 32],  sBL[2][NT * 32];

  int tid = threadIdx.x, lane = tid & 63, wave = tid >> 6;
  int wr = (wave >> 1) * 64, wc = (wave & 1) * (NT >> 1);
  int l15 = lane & 15, l4 = lane >> 4;

  f32x4 acc[4][NF];
#pragma unroll
  for (int m = 0; m < 4; ++m)
#pragma unroll
    for (int n = 0; n < NF; ++n) acc[m][n] = (f32x4){0.f, 0.f, 0.f, 0.f};

  auto stageG = [&](int buf, int k0) {
#pragma unroll
    for (int i = 0; i < 2; ++i) {
      int fi = i * 2048 + tid * 8;
      int r = fi >> 5, chk = (fi >> 3) & 3;
      int scol = ((chk ^ ((r >> 1) & 3)) << 3);
      int ra = m0 + r; if (ra > M - 1) ra = M - 1;
      long long go = (long long)ra * lda + k0 + scol;
      gld16(AHp + go, &sAH[buf][fi]);
      gld16(ALp + go, &sAL[buf][fi]);
    }
#pragma unroll
    for (int i = 0; i < NT / 64; ++i) {
      int fi = i * 2048 + tid * 8;
      int r = fi >> 5, chk = (fi >> 3) & 3;
      int scol = ((chk ^ ((r >> 1) & 3)) << 3);
      int rb = n0 + r; if (rb > N - 1) rb = N - 1;
      long long go = (long long)rb * ldb + k0 + scol;
      gld16(BHp + go, &sBH[buf][fi]);
      gld16(BLp + go, &sBL[buf][fi]);
    }
  };

  int nIt = K >> 5;
  stageG(0, 0);
  for (int it = 0; it < nIt; ++it) {
    int cur = it & 1;
    __syncthreads();
    if (it + 1 < nIt) stageG(cur ^ 1, (it + 1) << 5);
    bf16x8 ah[4], al[4], bh[NF], bl[NF];
#pragma unroll
    for (int m = 0; m < 4; ++m) {
      int r = wr + m * 16 + l15;
      int o = r * 32 + ((l4 ^ ((r >> 1) & 3)) << 3);
      ah[m] = *(const bf16x8*)&sAH[cur][o];
      al[m] = *(const bf16x8*)&sAL[cur][o];
    }
#pragma unroll
    for (int n = 0; n < NF; ++n) {
      int r = wc + n * 16 + l15;
      int o = r * 32 + ((l4 ^ ((r >> 1) & 3)) << 3);
      bh[n] = *(const bf16x8*)&sBH[cur][o];
      bl[n] = *(const bf16x8*)&sBL[cur][o];
    }
#pragma unroll
    for (int m = 0; m < 4; ++m)
#pragma unroll
      for (int n = 0; n < NF; ++n) {
        acc[m][n] = MFMA(ah[m], bh[n], acc[m][n], 0, 0, 0);
        acc[m][n] = MFMA(al[m], bh[n], acc[m][n], 0, 0, 0);
        acc[m][n] = MFMA(ah[m], bl[n], acc[m][n], 0, 0, 0);
      }
  }

  if (EPI == 5 && n0 >= 2 * DM) {
#pragma unroll
    for (int m = 0; m < 4; ++m) {
      int rbase = m0 + wr + m * 16 + l4 * 4;
#pragma unroll
      for (int n = 0; n < NF; ++n) {
        int c = n0 + wc + n * 16 + l15;
        int d = c - 2 * DM;
        float bv = bias[c];
        s4v hv, lv;
#pragma unroll
        for (int q = 0; q < 4; ++q) {
          ushort_t hh, ll; split2(acc[m][n][q] + bv, hh, ll);
          hv[q] = (short)hh; lv[q] = (short)ll;
        }
        *(s4v*)&TH[(long long)d * SQ + rbase] = hv;
        *(s4v*)&TL[(long long)d * SQ + rbase] = lv;
      }
    }
    return;
  }

#pragma unroll
  for (int m = 0; m < 4; ++m) {
#pragma unroll
    for (int n = 0; n < NF; ++n) {
      int c = n0 + wc + n * 16 + l15;
      if (c >= N) continue;
      float bv = (EPI == 4 || EPI == 5) ? bias[c] : 0.f;
#pragma unroll
      for (int q = 0; q < 4; ++q) {
        int rr = m0 + wr + m * 16 + l4 * 4 + q;
        if (rr >= M) continue;
        float v = acc[m][n][q];
        if (EPI == 5) {
          ushort_t hh, ll; split2(v + bv, hh, ll);
          long long o = (long long)rr * ldc + c; CH[o] = hh; CL[o] = ll;
        } else if (EPI == 2) {
          C[(long long)kc * pC + (long long)rr * ldc + (long long)h * bC + c] = v;
        } else if (EPI == 4) {
          ushort_t hh, ll; split2(geluf(v + bv), hh, ll);
          long long o = (long long)rr * ldc + c; CH[o] = hh; CL[o] = ll;
        }
      }
    }
  }
}

#define SP_ARGS const ushort_t* AH, const ushort_t* AL, int lda, long long bA, \
    const ushort_t* BH, const ushort_t* BL, int ldb, long long bB, \
    float* C, ushort_t* CH, ushort_t* CL, int ldc, long long bC, long long pC, \
    int M, int N, int K, const float* bias, float alpha, \
    ushort_t* TH, ushort_t* TL
#define SP_PASS AH, AL, lda, bA, BH, BL, ldb, bB, C, CH, CL, ldc, bC, pC, M, N, K, bias, alpha, TH, TL

__global__ __launch_bounds__(256) void k_qkv (SP_ARGS) { gemmsp_body<5,128,1>(SP_PASS); }
__global__ __launch_bounds__(256) void k_outp(SP_ARGS) { gemmsp_body<2, 64,4>(SP_PASS); }
__global__ __launch_bounds__(256) void k_ffn1(SP_ARGS) { gemmsp_body<4,128,1>(SP_PASS); }
__global__ __launch_bounds__(256) void k_ffn2(SP_ARGS) { gemmsp_body<2, 64,2>(SP_PASS); }

// ---------------------------------------------------------------------------
// Fused flash attention, split-f32 precision. Grid (32,16). K/V dbuf.
// ---------------------------------------------------------------------------
__global__ __launch_bounds__(256)
void k_attn(const ushort_t* __restrict__ qkvH, const ushort_t* __restrict__ qkvL,
            const ushort_t* __restrict__ VtH, const ushort_t* __restrict__ VtL,
            ushort_t* __restrict__ aH, ushort_t* __restrict__ aL)
{
  int f = blockIdx.x + blockIdx.y * gridDim.x;
  int logical = (f & 7) * 64 + (f >> 3);
  int q0 = (logical & 31) * 64;
  int h  = logical >> 5;

  __shared__ __align__(16) ushort_t sKH[2][4096], sKL[2][4096];
  __shared__ __align__(16) ushort_t sVH[2][4096], sVL[2][4096];
  __shared__ __align__(16) ushort_t sPH[4096], sPL[4096];

  int tid = threadIdx.x, lane = tid & 63, wave = tid >> 6;
  int l15 = lane & 15, l4 = lane >> 4;

  bf16x8 qh[2], ql[2];
  {
    long long base = (long long)(q0 + wave * 16 + l15) * (3 * DM) + h * 64 + l4 * 8;
    qh[0] = *(const bf16x8*)(qkvH + base);
    qh[1] = *(const bf16x8*)(qkvH + base + 32);
    ql[0] = *(const bf16x8*)(qkvL + base);
    ql[1] = *(const bf16x8*)(qkvL + base + 32);
  }

  auto stageKV = [&](int buf, int kt) {
#pragma unroll
    for (int i = 0; i < 2; ++i) {
      int idx = i * 2048 + tid * 8;
      int row = idx >> 6, chk = (idx >> 3) & 7;
      int scol = ((chk ^ (row & 7)) << 3);
      long long gk = (long long)(kt * 64 + row) * (3 * DM) + DM + h * 64 + scol;
      long long gv = (long long)(h * 64 + row) * SQ + kt * 64 + scol;
      gld16(qkvH + gk, &sKH[buf][idx]);
      gld16(qkvL + gk, &sKL[buf][idx]);
      gld16(VtH + gv, &sVH[buf][idx]);
      gld16(VtL + gv, &sVL[buf][idx]);
    }
  };

  float mrow[4], lrow[4];
  f32x4 Oacc[4];
#pragma unroll
  for (int r = 0; r < 4; ++r) { mrow[r] = -1e30f; lrow[r] = 0.f; }
#pragma unroll
  for (int n = 0; n < 4; ++n) Oacc[n] = (f32x4){0.f, 0.f, 0.f, 0.f};

  const int NT = SQ / 64;
  stageKV(0, 0);
  for (int kt = 0; kt < NT; ++kt) {
    int cur = kt & 1;
    __syncthreads();
    if (kt + 1 < NT) stageKV(cur ^ 1, kt + 1);

    f32x4 S[4];
#pragma unroll
    for (int n = 0; n < 4; ++n) S[n] = (f32x4){0.f, 0.f, 0.f, 0.f};
#pragma unroll
    for (int kk = 0; kk < 64; kk += 32) {
      int kkI = kk >> 5;
      bf16x8 qhf = qh[kkI], qlf = ql[kkI];
#pragma unroll
      for (int n = 0; n < 4; ++n) {
        int br = n * 16 + l15;
        int bo = br * 64 + ((((kk >> 3) + l4) ^ (br & 7)) << 3);
        bf16x8 kh = *(const bf16x8*)&sKH[cur][bo];
        bf16x8 kl = *(const bf16x8*)&sKL[cur][bo];
        S[n] = MFMA(qhf, kh, S[n], 0, 0, 0);
        S[n] = MFMA(qlf, kh, S[n], 0, 0, 0);
        S[n] = MFMA(qhf, kl, S[n], 0, 0, 0);
      }
    }
    float tm[4], ts[4];
#pragma unroll
    for (int r = 0; r < 4; ++r) {
#pragma unroll
      for (int n = 0; n < 4; ++n) S[n][r] *= 0.125f;
      tm[r] = fmaxf(fmaxf(S[0][r], S[1][r]), fmaxf(S[2][r], S[3][r]));
    }
#pragma unroll
    for (int mk = 1; mk <= 8; mk <<= 1)
#pragma unroll
      for (int r = 0; r < 4; ++r) tm[r] = fmaxf(tm[r], __shfl_xor(tm[r], mk));
#pragma unroll
    for (int r = 0; r < 4; ++r) {
      float mn = fmaxf(mrow[r], tm[r]);
      float corr = __expf(mrow[r] - mn);
      mrow[r] = mn;
      float s = 0.f;
#pragma unroll
      for (int n = 0; n < 4; ++n) { S[n][r] = __expf(S[n][r] - mn); s += S[n][r]; }
      ts[r] = s;
      lrow[r] *= corr;
#pragma unroll
      for (int n = 0; n < 4; ++n) Oacc[n][r] *= corr;
    }
#pragma unroll
    for (int mk = 1; mk <= 8; mk <<= 1)
#pragma unroll
      for (int r = 0; r < 4; ++r) ts[r] += __shfl_xor(ts[r], mk);
#pragma unroll
    for (int r = 0; r < 4; ++r) lrow[r] += ts[r];

    {
      ushort_t* pH = &sPH[wave * 1024];
      ushort_t* pL = &sPL[wave * 1024];
#pragma unroll
      for (int n = 0; n < 4; ++n)
#pragma unroll
        for (int r = 0; r < 4; ++r) {
          int row = l4 * 4 + r, col = n * 16 + l15;
          int ad = row * 64 + (((col >> 3) ^ (row & 7)) << 3) + (col & 7);
          ushort_t hh, ll; split2(S[n][r], hh, ll);
          pH[ad] = hh; pL[ad] = ll;
        }
    }
    __syncthreads();
#pragma unroll
    for (int kk = 0; kk < 64; kk += 32) {
      int ao = wave * 1024 + l15 * 64 + ((((kk >> 3) + l4) ^ (l15 & 7)) << 3);
      bf16x8 ph = *(const bf16x8*)&sPH[ao];
      bf16x8 pl = *(const bf16x8*)&sPL[ao];
#pragma unroll
      for (int n = 0; n < 4; ++n) {
        int br = n * 16 + l15;
        int bo = br * 64 + ((((kk >> 3) + l4) ^ (br & 7)) << 3);
        bf16x8 vh = *(const bf16x8*)&sVH[cur][bo];
        bf16x8 vl = *(const bf16x8*)&sVL[cur][bo];
        Oacc[n] = MFMA(ph, vh, Oacc[n], 0, 0, 0);
        Oacc[n] = MFMA(pl, vh, Oacc[n], 0, 0, 0);
        Oacc[n] = MFMA(ph, vl, Oacc[n], 0, 0, 0);
      }
    }
  }

#pragma unroll
  for (int n = 0; n < 4; ++n)
#pragma unroll
    for (int r = 0; r < 4; ++r) {
      int q = q0 + wave * 16 + l4 * 4 + r;
      int d = h * 64 + n * 16 + l15;
      float val = Oacc[n][r] / lrow[r];
      ushort_t hh, ll; split2(val, hh, ll);
      long long o = (long long)q * DM + d;
      aH[o] = hh; aL[o] = ll;
    }
}

// ---------------------------------------------------------------------------
// bf16 GEMM engine "s" (MoE): BM=128, BK=32, 32KB LDS -> 5 blocks/CU.
// ---------------------------------------------------------------------------
template<int EPI, int SWAP, int KS>
__device__ __forceinline__ void gemm16s_body(
    const ushort_t* __restrict__ A, int lda, long long bA,
    const ushort_t* __restrict__ Bp0, int ldb, long long bB,
    void* __restrict__ Cv, int ldc, long long bC, long long pC,
    int M, int N, int K, const float* __restrict__ bias, int bBias,
    const int* __restrict__ offs)
{
  int bz = blockIdx.z;
  int z = bz / KS, kc = bz % KS;
  int Kc = K / KS;
  const ushort_t* Ap = A + (long long)z * bA + (long long)kc * Kc;
  const ushort_t* Bp = Bp0 + (long long)z * bB + (long long)kc * Kc;
  int rowStart = 0, Meff = M;
  if (offs) { rowStart = offs[z]; Meff = offs[z + 1] - rowStart; }
  int m0 = (SWAP ? blockIdx.y : blockIdx.x) * 128;
  if (m0 >= Meff) return;
  int n0 = (SWAP ? blockIdx.x : blockIdx.y) * 128;

  __shared__ __align__(16) char smem[32768];

  int tid = threadIdx.x, lane = tid & 63, wave = tid >> 6;
  int wr = (wave >> 1) * 64, wc = (wave & 1) * 64;
  int l15 = lane & 15, l4 = lane >> 4;

  f32x4 acc[4][4];
#pragma unroll
  for (int m = 0; m < 4; ++m)
#pragma unroll
    for (int n = 0; n < 4; ++n) acc[m][n] = (f32x4){0.f, 0.f, 0.f, 0.f};

  auto stageG = [&](int buf, int k0) {
    ushort_t* dA = (ushort_t*)(smem + buf * 8192);
    ushort_t* dB = (ushort_t*)(smem + 16384 + buf * 8192);
#pragma unroll
    for (int i = 0; i < 2; ++i) {
      int idx = i * 2048 + tid * 8;
      int row = idx >> 5, chk = (idx >> 3) & 3;
      int scol = ((chk ^ ((row >> 1) & 3)) << 3);
      int ra = m0 + row; if (ra > Meff - 1) ra = Meff - 1;
      gld16(Ap + (long long)(rowStart + ra) * lda + k0 + scol, &dA[idx]);
    }
#pragma unroll
    for (int i = 0; i < 2; ++i) {
      int idx = i * 2048 + tid * 8;
      int row = idx >> 5, chk = (idx >> 3) & 3;
      int scol = ((chk ^ ((row >> 1) & 3)) << 3);
      int rb = n0 + row; if (rb > N - 1) rb = N - 1;
      gld16(Bp + (long long)rb * ldb + k0 + scol, &dB[idx]);
    }
  };

  int nIt = Kc >> 5;
  stageG(0, 0);
  for (int it = 0; it < nIt; ++it) {
    int cur = it & 1;
    __syncthreads();
    if (it + 1 < nIt) stageG(cur ^ 1, (it + 1) << 5);
    ushort_t* As = (ushort_t*)(smem + cur * 8192);
    ushort_t* Bs = (ushort_t*)(smem + 16384 + cur * 8192);
    bf16x8 af[4], bfr[4];
#pragma unroll
    for (int m = 0; m < 4; ++m) {
      int r = wr + m * 16 + l15;
      af[m] = *(const bf16x8*)&As[r * 32 + ((l4 ^ ((r >> 1) & 3)) << 3)];
    }
#pragma unroll
    for (int n = 0; n < 4; ++n) {
      int r = wc + n * 16 + l15;
      bfr[n] = *(const bf16x8*)&Bs[r * 32 + ((l4 ^ ((r >> 1) & 3)) << 3)];
    }
#pragma unroll
    for (int m = 0; m < 4; ++m)
#pragma unroll
      for (int n = 0; n < 4; ++n)
        acc[m][n] = MFMA(af[m], bfr[n], acc[m][n], 0, 0, 0);
  }
  __syncthreads();

  if (EPI == 7) {
    float* fE = (float*)smem;
#pragma unroll
    for (int h2 = 0; h2 < 2; ++h2) {
      if ((wave >> 1) == h2) {
#pragma unroll
        for (int m = 0; m < 4; ++m)
#pragma unroll
          for (int n = 0; n < 4; ++n)
#pragma unroll
            for (int q = 0; q < 4; ++q)
              fE[(m * 16 + l4 * 4 + q) * 128 + wc + n * 16 + l15] = acc[m][n][q];
      }
      __syncthreads();
#pragma unroll
      for (int i = 0; i < 8; ++i) {
        int lin = tid + i * 256;
        int row = lin >> 5, c4 = (lin & 31) << 2;
        int gr = m0 + h2 * 64 + row;
        if (gr < Meff) {
          f32x4 v4 = *(const f32x4*)&fE[row * 128 + c4];
          long long crow = rowStart + gr;
          float* dst = (float*)Cv + (long long)kc * pC + crow * ldc + n0 + c4;
          *(f32x4*)dst = v4;
        }
      }
      __syncthreads();
    }
    return;
  }

#pragma unroll
  for (int m = 0; m < 4; ++m) {
#pragma unroll
    for (int n = 0; n < 4; ++n) {
      int c = n0 + wc + n * 16 + l15;
      if (c >= N) continue;
      float bv = (EPI == 2) ? bias[(long long)z * bBias + c] : 0.f;
#pragma unroll
      for (int q = 0; q < 4; ++q) {
        int rr = m0 + wr + m * 16 + l4 * 4 + q;
        if (rr >= Meff) continue;
        float v = acc[m][n][q];
        long long crow = rowStart + rr;
        if (EPI == 2)
          ((ushort_t*)Cv)[crow * ldc + (long long)z * bC + c] = f2b(geluf(v + bv));
      }
    }
  }
}

// ---------------------------------------------------------------------------
// bf16 GEMM engine "w8" (head, bf16 B only): BM=256 x BN=128, BK=32, wave tile
// 128x64, depth-2 counted-vmcnt pipeline (T3+T4): per iter
//   ds_read frags(tile t) -> lgkmcnt(0)+barrier -> stage tile t+2 into freed
//   buffer -> 32 MFMA -> vmcnt(6) (tile t+1 landed; t+2 stays in flight) ->
//   barrier. vmcnt never drains to 0 in steady state.
// 6 gld16/thread per tile (4 A + 2 B); vmcnt(6) == one tile in flight.
// ---------------------------------------------------------------------------
__device__ __forceinline__ void gemm16w8_body(
    const ushort_t* __restrict__ A, int lda,
    const ushort_t* __restrict__ Bp, int ldb,
    float* __restrict__ Cv, int ldc,
    int M, int N, int K)
{
  int bx = blockIdx.x, by = blockIdx.y;
  {
    int flat = bx + by * gridDim.x;
    int cpx = (gridDim.x * gridDim.y) >> 3;
    int s = (flat & 7) * cpx + (flat >> 3);
    bx = s % gridDim.x; by = s / gridDim.x;
  }
  int m0 = bx * 256;
  int n0 = by * 128;

  __shared__ __align__(16) char smem[49152];  // A: 2x16KB, B: 2x8KB

  int tid = threadIdx.x, lane = tid & 63, wave = tid >> 6;
  int wr = (wave >> 1) * 128, wc = (wave & 1) * 64;
  int l15 = lane & 15, l4 = lane >> 4;

  f32x4 acc[8][4];
#pragma unroll
  for (int m = 0; m < 8; ++m)
#pragma unroll
    for (int n = 0; n < 4; ++n) acc[m][n] = (f32x4){0.f, 0.f, 0.f, 0.f};

  auto stageG = [&](int buf, int k0) {
    ushort_t* dA = (ushort_t*)(smem + buf * 16384);
    ushort_t* dB = (ushort_t*)(smem + 32768 + buf * 8192);
#pragma unroll
    for (int i = 0; i < 4; ++i) {            // A: 256x32
      int idx = i * 2048 + tid * 8;
      int row = idx >> 5, chk = (idx >> 3) & 3;
      int scol = ((chk ^ ((row >> 1) & 3)) << 3);
      int ra = m0 + row; if (ra > M - 1) ra = M - 1;
      gld16(A + (long long)ra * lda + k0 + scol, &dA[idx]);
    }
#pragma unroll
    for (int i = 0; i < 2; ++i) {            // B: 128x32
      int idx = i * 2048 + tid * 8;
      int row = idx >> 5, chk = (idx >> 3) & 3;
      int scol = ((chk ^ ((row >> 1) & 3)) << 3);
      int rb = n0 + row; if (rb > N - 1) rb = N - 1;
      gld16(Bp + (long long)rb * ldb + k0 + scol, &dB[idx]);
    }
  };

  int nIt = K >> 5;                          // 32
  stageG(0, 0);
  stageG(1, 32);                             // 12 loads/thread in flight
  asm volatile("s_waitcnt vmcnt(6)" ::: "memory");   // tile0 landed
  __builtin_amdgcn_s_barrier();
  __builtin_amdgcn_sched_barrier(0);

  for (int it = 0; it < nIt; ++it) {
    int cur = it & 1;
    ushort_t* As = (ushort_t*)(smem + cur * 16384);
    ushort_t* Bs = (ushort_t*)(smem + 32768 + cur * 8192);
    bf16x8 af[8], bfr[4];
#pragma unroll
    for (int m = 0; m < 8; ++m) {
      int r = wr + m * 16 + l15;
      af[m] = *(const bf16x8*)&As[r * 32 + ((l4 ^ ((r >> 1) & 3)) << 3)];
    }
#pragma unroll
    for (int n = 0; n < 4; ++n) {
      int r = wc + n * 16 + l15;
      bfr[n] = *(const bf16x8*)&Bs[r * 32 + ((l4 ^ ((r >> 1) & 3)) << 3)];
    }
    // frags in regs; free buf[cur] for tile it+2
    asm volatile("s_waitcnt lgkmcnt(0)" ::: "memory");
    __builtin_amdgcn_sched_barrier(0);
    __builtin_amdgcn_s_barrier();            // all waves done reading buf[cur]
    __builtin_amdgcn_sched_barrier(0);
    if (it + 2 < nIt) stageG(cur, (it + 2) << 5);
#pragma unroll
    for (int m = 0; m < 8; ++m)
#pragma unroll
      for (int n = 0; n < 4; ++n)
        acc[m][n] = MFMA(af[m], bfr[n], acc[m][n], 0, 0, 0);
    if (it + 1 < nIt) {
      if (it + 2 < nIt)
        asm volatile("s_waitcnt vmcnt(6)" ::: "memory");  // tile it+1 landed
      else
        asm volatile("s_waitcnt vmcnt(0)" ::: "memory");  // drain tail
      __builtin_amdgcn_s_barrier();
      __builtin_amdgcn_sched_barrier(0);
    }
  }
  __syncthreads();   // full drain before epilogue LDS reuse

  // LDS-transpose epilogue: 4 passes of 64x128 f32, non-temporal float4 stores
  float* fE = (float*)smem;
#pragma unroll
  for (int h2 = 0; h2 < 4; ++h2) {
    if ((wave >> 1) == (h2 >> 1)) {
#pragma unroll
      for (int mm = 0; mm < 4; ++mm) {
        int m = (h2 & 1) * 4 + mm;
#pragma unroll
        for (int n = 0; n < 4; ++n)
#pragma unroll
          for (int q = 0; q < 4; ++q)
            fE[(mm * 16 + l4 * 4 + q) * 128 + wc + n * 16 + l15] = acc[m][n][q];
      }
    }
    __syncthreads();
#pragma unroll
    for (int i = 0; i < 8; ++i) {
      int lin = tid + i * 256;
      int row = lin >> 5, c4 = (lin & 31) << 2;
      int gr = m0 + h2 * 64 + row;
      if (gr < M) {
        f32x4 v4 = *(const f32x4*)&fE[row * 128 + c4];
        float* dst = Cv + (long long)gr * ldc + n0 + c4;
        __builtin_nontemporal_store(v4, (f32x4*)dst);
      }
    }
    __syncthreads();
  }
}

// ---------------------------------------------------------------------------
// bf16 GEMM engine "w" (head fallback, f32 B reg-staged): r17 plain 2-phase.
// ---------------------------------------------------------------------------
__device__ __forceinline__ void gemm16w_body_f(
    const ushort_t* __restrict__ A, int lda,
    const float* __restrict__ Bf, int ldb,
    float* __restrict__ Cv, int ldc,
    int M, int N, int K)
{
  int bx = blockIdx.x, by = blockIdx.y;
  {
    int flat = bx + by * gridDim.x;
    int cpx = (gridDim.x * gridDim.y) >> 3;
    int s = (flat & 7) * cpx + (flat >> 3);
    bx = s % gridDim.x; by = s / gridDim.x;
  }
  int m0 = bx * 256;
  int n0 = by * 128;

  __shared__ __align__(16) char smem[49152];

  int tid = threadIdx.x, lane = tid & 63, wave = tid >> 6;
  int wr = (wave >> 1) * 128, wc = (wave & 1) * 64;
  int l15 = lane & 15, l4 = lane >> 4;

  f32x4 acc[8][4];
#pragma unroll
  for (int m = 0; m < 8; ++m)
#pragma unroll
    for (int n = 0; n < 4; ++n) acc[m][n] = (f32x4){0.f, 0.f, 0.f, 0.f};

  auto stageG = [&](int buf, int k0) {
    ushort_t* dA = (ushort_t*)(smem + buf * 16384);
    ushort_t* dB = (ushort_t*)(smem + 32768 + buf * 8192);
#pragma unroll
    for (int i = 0; i < 4; ++i) {
      int idx = i * 2048 + tid * 8;
      int row = idx >> 5, chk = (idx >> 3) & 3;
      int scol = ((chk ^ ((row >> 1) & 3)) << 3);
      int ra = m0 + row; if (ra > M - 1) ra = M - 1;
      gld16(A + (long long)ra * lda + k0 + scol, &dA[idx]);
    }
#pragma unroll
    for (int i = 0; i < 4; ++i) {
      int g = tid + i * 256;
      int r = g >> 3, c4 = (g & 7) * 4;
      int rb = n0 + r; if (rb > N - 1) rb = N - 1;
      float4 fv = *(const float4*)(Bf + (long long)rb * ldb + k0 + c4);
      s4v o; o[0] = (short)f2b(fv.x); o[1] = (short)f2b(fv.y);
      o[2] = (short)f2b(fv.z); o[3] = (short)f2b(fv.w);
      int dst = r * 32 + ((((c4 >> 3) ^ ((r >> 1) & 3))) << 3) + (c4 & 7);
      *(s4v*)&dB[dst] = o;
    }
  };

  int nIt = K >> 5;
  stageG(0, 0);
  for (int it = 0; it < nIt; ++it) {
    int cur = it & 1;
    __syncthreads();
    if (it + 1 < nIt) stageG(cur ^ 1, (it + 1) << 5);
    ushort_t* As = (ushort_t*)(smem + cur * 16384);
    ushort_t* Bs = (ushort_t*)(smem + 32768 + cur * 8192);
    bf16x8 af[8], bfr[4];
#pragma unroll
    for (int m = 0; m < 8; ++m) {
      int r = wr + m * 16 + l15;
      af[m] = *(const bf16x8*)&As[r * 32 + ((l4 ^ ((r >> 1) & 3)) << 3)];
    }
#pragma unroll
    for (int n = 0; n < 4; ++n) {
      int r = wc + n * 16 + l15;
      bfr[n] = *(const bf16x8*)&Bs[r * 32 + ((l4 ^ ((r >> 1) & 3)) << 3)];
    }
#pragma unroll
    for (int m = 0; m < 8; ++m)
#pragma unroll
      for (int n = 0; n < 4; ++n)
        acc[m][n] = MFMA(af[m], bfr[n], acc[m][n], 0, 0, 0);
  }
  __syncthreads();

  float* fE = (float*)smem;
#pragma unroll
  for (int h2 = 0; h2 < 4; ++h2) {
    if ((wave >> 1) == (h2 >> 1)) {
#pragma unroll
      for (int mm = 0; mm < 4; ++mm) {
        int m = (h2 & 1) * 4 + mm;
#pragma unroll
        for (int n = 0; n < 4; ++n)
#pragma unroll
          for (int q = 0; q < 4; ++q)
            fE[(mm * 16 + l4 * 4 + q) * 128 + wc + n * 16 + l15] = acc[m][n][q];
      }
    }
    __syncthreads();
#pragma unroll
    for (int i = 0; i < 8; ++i) {
      int lin = tid + i * 256;
      int row = lin >> 5, c4 = (lin & 31) << 2;
      int gr = m0 + h2 * 64 + row;
      if (gr < M) {
        f32x4 v4 = *(const f32x4*)&fE[row * 128 + c4];
        float* dst = Cv + (long long)gr * ldc + n0 + c4;
        __builtin_nontemporal_store(v4, (f32x4*)dst);
      }
    }
    __syncthreads();
  }
}

#define G16_ARGS const ushort_t* A, int lda, long long bA, const void* Bv, \
    int ldb, long long bB, void* Cv, int ldc, long long bC, long long pC, \
    int M, int N, int K, const float* bias, int bBias, const int* offs
#define G16S_PASS(EPI,SWAP,KS) gemm16s_body<EPI,SWAP,KS>(A, lda, bA, \
    (const ushort_t*)Bv, ldb, bB, Cv, ldc, bC, pC, M, N, K, bias, bBias, offs)

__global__ __launch_bounds__(256) void k_moe1(G16_ARGS) { G16S_PASS(2,1,1); }
__global__ __launch_bounds__(256) void k_moe2(G16_ARGS) { G16S_PASS(7,1,2); }
__global__ __launch_bounds__(256) void k_head_bf(G16_ARGS) {
  gemm16w8_body(A, lda, (const ushort_t*)Bv, ldb, (float*)Cv, ldc, M, N, K);
}
__global__ __launch_bounds__(256) void k_head_f(G16_ARGS) {
  gemm16w_body_f(A, lda, (const float*)Bv, ldb, (float*)Cv, ldc, M, N, K);
}

// ---------------------------------------------------------------------------
__global__ __launch_bounds__(256)
void cvt_split2(const float* __restrict__ s0, ushort_t* __restrict__ dh0,
                ushort_t* __restrict__ dl0,
                const float* __restrict__ s1, ushort_t* __restrict__ dh1,
                ushort_t* __restrict__ dl1, int n4)
{
  const float* s = blockIdx.y ? s1 : s0;
  ushort_t* dh = blockIdx.y ? dh1 : dh0;
  ushort_t* dl = blockIdx.y ? dl1 : dl0;
  int i = blockIdx.x * blockDim.x + threadIdx.x;
  int stride = gridDim.x * blockDim.x;
  for (; i < n4; i += stride) {
    float4 f = ((const float4*)s)[i];
    s4v h, l; ushort_t hh, ll;
    split2(f.x, hh, ll); h[0] = (short)hh; l[0] = (short)ll;
    split2(f.y, hh, ll); h[1] = (short)hh; l[1] = (short)ll;
    split2(f.z, hh, ll); h[2] = (short)hh; l[2] = (short)ll;
    split2(f.w, hh, ll); h[3] = (short)hh; l[3] = (short)ll;
    ((s4v*)dh)[i] = h; ((s4v*)dl)[i] = l;
  }
}

__global__ __launch_bounds__(256)
void cvt_bf16(const float* __restrict__ s, ushort_t* __restrict__ d, int n4)
{
  int i = blockIdx.x * blockDim.x + threadIdx.x;
  int stride = gridDim.x * blockDim.x;
  for (; i < n4; i += stride) {
    float4 f = ((const float4*)s)[i];
    s4v o; o[0] = (short)f2b(f.x); o[1] = (short)f2b(f.y);
    o[2] = (short)f2b(f.z); o[3] = (short)f2b(f.w);
    ((s4v*)d)[i] = o;
  }
}

__global__ __launch_bounds__(256)
void cvt_bf16_2(const float* __restrict__ s0, ushort_t* __restrict__ d0,
                const float* __restrict__ s1, ushort_t* __restrict__ d1, int n4)
{
  const float* s = blockIdx.y ? s1 : s0;
  ushort_t* d = blockIdx.y ? d1 : d0;
  int i = blockIdx.x * blockDim.x + threadIdx.x;
  int stride = gridDim.x * blockDim.x;
  for (; i < n4; i += stride) {
    float4 f = ((const float4*)s)[i];
    s4v o; o[0] = (short)f2b(f.x); o[1] = (short)f2b(f.y);
    o[2] = (short)f2b(f.z); o[3] = (short)f2b(f.w);
    ((s4v*)d)[i] = o;
  }
}

__global__ __launch_bounds__(256)
void embed_kernel(const int* __restrict__ ids, const float* __restrict__ ew,
                  const float* __restrict__ pw, float* __restrict__ x,
                  int* __restrict__ counts)
{
  int srow = blockIdx.x, tid = threadIdx.x;
  if (srow == 0 && tid < 8) counts[tid] = 0;
  int id = ids[srow];
  const float4 e = *(const float4*)(ew + (long long)id * DM + tid * 4);
  const float4 p = *(const float4*)(pw + (long long)srow * DM + tid * 4);
  float4* xr = (float4*)(x + (long long)srow * DM) + tid;
  *xr = make_float4(e.x + p.x, e.y + p.y, e.z + p.z, e.w + p.w);
}

template<int MODE, int NP>
__global__ __launch_bounds__(256)
void ln_fused(float* __restrict__ x, const float* __restrict__ P, long long pC,
              const float* __restrict__ bias_pre,
              const float* __restrict__ g, const float* __restrict__ b,
              ushort_t* __restrict__ outH, ushort_t* __restrict__ outL)
{
  int row = blockIdx.x, tid = threadIdx.x;
  long long xo = (long long)row * DM + tid * 4;
  float4 v = *(const float4*)(x + xo);
  if (NP > 0) {
    float4 bp = *(const float4*)(bias_pre + tid * 4);
    float sx = bp.x, sy = bp.y, sz = bp.z, sw = bp.w;
#pragma unroll
    for (int p = 0; p < NP; ++p) {
      float4 pv = *(const float4*)(P + (long long)p * pC + xo);
      sx += pv.x; sy += pv.y; sz += pv.z; sw += pv.w;
    }
    v.x += sx; v.y += sy; v.z += sz; v.w += sw;
    *(float4*)(x + xo) = v;
  }
  __shared__ float sm1[4], sm2[4];
  float s = v.x + v.y + v.z + v.w;
  for (int o = 32; o > 0; o >>= 1) s += __shfl_down(s, o);
  if ((tid & 63) == 0) sm1[tid >> 6] = s;
  __syncthreads();
  float mean = (sm1[0] + sm1[1] + sm1[2] + sm1[3]) * (1.0f / DM);
  float d0 = v.x - mean, d1 = v.y - mean, d2 = v.z - mean, d3 = v.w - mean;
  float q = d0 * d0 + d1 * d1 + d2 * d2 + d3 * d3;
  for (int o = 32; o > 0; o >>= 1) q += __shfl_down(q, o);
  if ((tid & 63) == 0) sm2[tid >> 6] = q;
  __syncthreads();
  float var = (sm2[0] + sm2[1] + sm2[2] + sm2[3]) * (1.0f / DM);
  float rstd = rsqrtf(var + 1e-5f);
  float4 gv = ((const float4*)g)[tid];
  float4 bv = ((const float4*)b)[tid];
  float o0 = d0 * rstd * gv.x + bv.x, o1 = d1 * rstd * gv.y + bv.y;
  float o2 = d2 * rstd * gv.z + bv.z, o3 = d3 * rstd * gv.w + bv.w;
  long long base = (long long)row * DM + tid * 4;
  if (MODE == 0) {
    ushort_t hh, ll;
    split2(o0, hh, ll); outH[base + 0] = hh; outL[base + 0] = ll;
    split2(o1, hh, ll); outH[base + 1] = hh; outL[base + 1] = ll;
    split2(o2, hh, ll); outH[base + 2] = hh; outL[base + 2] = ll;
    split2(o3, hh, ll); outH[base + 3] = hh; outL[base + 3] = ll;
  } else {
    outH[base + 0] = f2b(o0); outH[base + 1] = f2b(o1);
    outH[base + 2] = f2b(o2); outH[base + 3] = f2b(o3);
  }
}

__global__ __launch_bounds__(256)
void ln_gate_top2(float* __restrict__ x, const float* __restrict__ P,
                  long long pC, const float* __restrict__ bias_pre,
                  const float* __restrict__ g, const float* __restrict__ b,
                  const float* __restrict__ gw, const float* __restrict__ gb,
                  int* __restrict__ topi, float* __restrict__ topw,
                  int* __restrict__ counts, ushort_t* __restrict__ outH)
{
  int row = blockIdx.x, tid = threadIdx.x;
  long long xo = (long long)row * DM + tid * 4;
  float4 v = *(const float4*)(x + xo);
  {
    float4 bp = *(const float4*)(bias_pre + tid * 4);
    float sx = bp.x, sy = bp.y, sz = bp.z, sw = bp.w;
#pragma unroll
    for (int p = 0; p < 4; ++p) {
      float4 pv = *(const float4*)(P + (long long)p * pC + xo);
      sx += pv.x; sy += pv.y; sz += pv.z; sw += pv.w;
    }
    v.x += sx; v.y += sy; v.z += sz; v.w += sw;
    *(float4*)(x + xo) = v;
  }
  __shared__ float sm1[4], sm2[4];
  __shared__ float se[8][4];
  float s = v.x + v.y + v.z + v.w;
  for (int o = 32; o > 0; o >>= 1) s += __shfl_down(s, o);
  if ((tid & 63) == 0) sm1[tid >> 6] = s;
  __syncthreads();
  float mean = (sm1[0] + sm1[1] + sm1[2] + sm1[3]) * (1.0f / DM);
  float d0 = v.x - mean, d1 = v.y - mean, d2 = v.z - mean, d3 = v.w - mean;
  float q = d0 * d0 + d1 * d1 + d2 * d2 + d3 * d3;
  for (int o = 32; o > 0; o >>= 1) q += __shfl_down(q, o);
  if ((tid & 63) == 0) sm2[tid >> 6] = q;
  __syncthreads();
  float var = (sm2[0] + sm2[1] + sm2[2] + sm2[3]) * (1.0f / DM);
  float rstd = rsqrtf(var + 1e-5f);
  float4 gv = ((const float4*)g)[tid];
  float4 bv = ((const float4*)b)[tid];
  float h0 = d0 * rstd * gv.x + bv.x, h1 = d1 * rstd * gv.y + bv.y;
  float h2 = d2 * rstd * gv.z + bv.z, h3 = d3 * rstd * gv.w + bv.w;
  long long base = (long long)row * DM + tid * 4;
  outH[base + 0] = f2b(h0); outH[base + 1] = f2b(h1);
  outH[base + 2] = f2b(h2); outH[base + 3] = f2b(h3);
#pragma unroll
  for (int e = 0; e < 8; ++e) {
    float4 w = ((const float4*)(gw + (long long)e * DM))[tid];
    float p = h0 * w.x + h1 * w.y + h2 * w.z + h3 * w.w;
    for (int o = 32; o > 0; o >>= 1) p += __shfl_down(p, o);
    if ((tid & 63) == 0) se[e][tid >> 6] = p;
  }
  __syncthreads();
  if (tid == 0) {
    float sc[8];
#pragma unroll
    for (int e = 0; e < 8; ++e)
      sc[e] = se[e][0] + se[e][1] + se[e][2] + se[e][3] + gb[e];
    int i1 = 0; float m1 = sc[0];
    for (int e = 1; e < 8; ++e) if (sc[e] > m1) { m1 = sc[e]; i1 = e; }
    int i2 = -1; float m2 = -1e30f;
    for (int e = 0; e < 8; ++e) if (e != i1 && sc[e] > m2) { m2 = sc[e]; i2 = e; }
    float e2 = __expf(m2 - m1);
    float w1 = 1.f / (1.f + e2);
    topi[row * 2] = i1; topi[row * 2 + 1] = i2;
    topw[row * 2] = w1; topw[row * 2 + 1] = 1.f - w1;
    atomicAdd(&counts[i1], 1);
    atomicAdd(&counts[i2], 1);
  }
}

__global__ void moe_prefix(const int* __restrict__ counts, int* __restrict__ offs,
                           int* __restrict__ cursors)
{
  if (threadIdx.x == 0 && blockIdx.x == 0) {
    int a = 0;
    for (int e = 0; e < 8; ++e) { offs[e] = a; a += counts[e]; cursors[e] = 0; }
    offs[8] = a;
  }
}

__global__ __launch_bounds__(256)
void moe_gather(const ushort_t* __restrict__ hH, const int* __restrict__ topi,
                const float* __restrict__ topw, const int* __restrict__ offs,
                int* __restrict__ cursors, int* __restrict__ tokIdx,
                float* __restrict__ tokW, int* __restrict__ slotOf,
                ushort_t* __restrict__ Xg)
{
  int tok = blockIdx.x, tid = threadIdx.x;
  __shared__ int s0s, s1s;
  if (tid == 0) {
    int e0 = topi[tok * 2], e1 = topi[tok * 2 + 1];
    int s0 = offs[e0] + atomicAdd(&cursors[e0], 1);
    int s1 = offs[e1] + atomicAdd(&cursors[e1], 1);
    tokIdx[s0] = tok; tokW[s0] = topw[tok * 2];
    tokIdx[s1] = tok; tokW[s1] = topw[tok * 2 + 1];
    slotOf[tok * 2] = s0; slotOf[tok * 2 + 1] = s1;
    s0s = s0; s1s = s1;
  }
  __syncthreads();
  s4v v = ((const s4v*)(hH + (long long)tok * DM))[tid];
  ((s4v*)(Xg + (long long)s0s * DM))[tid] = v;
  ((s4v*)(Xg + (long long)s1s * DM))[tid] = v;
}

__global__ __launch_bounds__(256)
void moe_ln_final(const float* __restrict__ x, const float* __restrict__ eo,
                  long long pC, const int* __restrict__ slotOf,
                  const int* __restrict__ topi, const float* __restrict__ topw,
                  const float* __restrict__ b2, const float* __restrict__ g,
                  const float* __restrict__ b, ushort_t* __restrict__ outH)
{
  int tok = blockIdx.x, tid = threadIdx.x;
  int s0 = slotOf[tok * 2], s1 = slotOf[tok * 2 + 1];
  int e0 = topi[tok * 2], e1 = topi[tok * 2 + 1];
  float w0 = topw[tok * 2], w1 = topw[tok * 2 + 1];
  float4 a  = ((const float4*)(eo + (long long)s0 * DM))[tid];
  float4 a2 = ((const float4*)(eo + pC + (long long)s0 * DM))[tid];
  float4 bb1= ((const float4*)(eo + (long long)s1 * DM))[tid];
  float4 bb2= ((const float4*)(eo + pC + (long long)s1 * DM))[tid];
  float4 ba = ((const float4*)(b2 + (long long)e0 * DM))[tid];
  float4 bbb= ((const float4*)(b2 + (long long)e1 * DM))[tid];
  float4 v = ((const float4*)(x + (long long)tok * DM))[tid];
  v.x += w0 * (a.x + a2.x + ba.x) + w1 * (bb1.x + bb2.x + bbb.x);
  v.y += w0 * (a.y + a2.y + ba.y) + w1 * (bb1.y + bb2.y + bbb.y);
  v.z += w0 * (a.z + a2.z + ba.z) + w1 * (bb1.z + bb2.z + bbb.z);
  v.w += w0 * (a.w + a2.w + ba.w) + w1 * (bb1.w + bb2.w + bbb.w);
  __shared__ float sm1[4], sm2[4];
  float s = v.x + v.y + v.z + v.w;
  for (int o = 32; o > 0; o >>= 1) s += __shfl_down(s, o);
  if ((tid & 63) == 0) sm1[tid >> 6] = s;
  __syncthreads();
  float mean = (sm1[0] + sm1[1] + sm1[2] + sm1[3]) * (1.0f / DM);
  float d0 = v.x - mean, d1 = v.y - mean, d2 = v.z - mean, d3 = v.w - mean;
  float q = d0 * d0 + d1 * d1 + d2 * d2 + d3 * d3;
  for (int o = 32; o > 0; o >>= 1) q += __shfl_down(q, o);
  if ((tid & 63) == 0) sm2[tid >> 6] = q;
  __syncthreads();
  float var = (sm2[0] + sm2[1] + sm2[2] + sm2[3]) * (1.0f / DM);
  float rstd = rsqrtf(var + 1e-5f);
  float4 gv = ((const float4*)g)[tid];
  float4 bv = ((const float4*)b)[tid];
  long long base = (long long)tok * DM + tid * 4;
  outH[base + 0] = f2b(d0 * rstd * gv.x + bv.x);
  outH[base + 1] = f2b(d1 * rstd * gv.y + bv.y);
  outH[base + 2] = f2b(d2 * rstd * gv.z + bv.z);
  outH[base + 3] = f2b(d3 * rstd * gv.w + bv.w);
}

extern "C" void kernel_launch(void* const* d_in, const int* in_sizes, int n_in,
                              void* d_out, int out_size, void* d_ws, size_t ws_size,
                              hipStream_t stream)
{
  const int* ids = (const int*)d_in[0];
  const float* embed_w = (const float*)d_in[1];
  const float* pos_w   = (const float*)d_in[2];
  const float* ln1_g[2] = {(const float*)d_in[3],  (const float*)d_in[11]};
  const float* ln1_b[2] = {(const float*)d_in[4],  (const float*)d_in[12]};
  const float* in_w[2]  = {(const float*)d_in[5],  (const float*)d_in[13]};
  const float* in_b[2]  = {(const float*)d_in[6],  (const float*)d_in[14]};
  const float* out_w[2] = {(const float*)d_in[7],  (const float*)d_in[15]};
  const float* out_b[2] = {(const float*)d_in[8],  (const float*)d_in[16]};
  const float* ln2_g[2] = {(const float*)d_in[9],  (const float*)d_in[17]};
  const float* ln2_b[2] = {(const float*)d_in[10], (const float*)d_in[18]};
  const float* ffn_w1 = (const float*)d_in[19];
  const float* ffn_b1 = (const float*)d_in[20];
  const float* ffn_w2 = (const float*)d_in[21];
  const float* ffn_b2 = (const float*)d_in[22];
  const float* gate_w = (const float*)d_in[23];
  const float* gate_b = (const float*)d_in[24];
  const float* moe_w1 = (const float*)d_in[25];
  const float* moe_b1 = (const float*)d_in[26];
  const float* moe_w2 = (const float*)d_in[27];
  const float* moe_b2 = (const float*)d_in[28];
  const float* norm_g = (const float*)d_in[29];
  const float* norm_b = (const float*)d_in[30];
  const float* head_w = (const float*)d_in[31];

  char* ob = (char*)d_out;
  size_t off = 0;
  auto alloc = [&](size_t bytes) {
    char* p = ob + off;
    off = (off + bytes + 255) & ~(size_t)255;
    return p;
  };
  float*    x      = (float*)alloc((size_t)SQ * DM * 4);
  ushort_t* hbufH  = (ushort_t*)alloc((size_t)SQ * DM * 2);
  ushort_t* hbufL  = (ushort_t*)alloc((size_t)SQ * DM * 2);
  ushort_t* qkvH   = (ushort_t*)alloc((size_t)SQ * 3 * DM * 2);   // ┐
  ushort_t* qkvL   = (ushort_t*)alloc((size_t)SQ * 3 * DM * 2);   // │ w2b
  ushort_t* VtH    = (ushort_t*)alloc((size_t)NH * HDIM * SQ * 2);// │ 64MiB
  ushort_t* VtL    = (ushort_t*)alloc((size_t)NH * HDIM * SQ * 2);// │
  char*     resv   = (char*)alloc((size_t)32 << 20);              // ┘ filler
  ushort_t* attnH  = (ushort_t*)alloc((size_t)SQ * DM * 2);
  ushort_t* attnL  = (ushort_t*)alloc((size_t)SQ * DM * 2);
  ushort_t* Xg     = (ushort_t*)alloc((size_t)2 * SQ * DM * 2);
  int*      topi   = (int*)alloc(SQ * 2 * 4);
  float*    topw   = (float*)alloc(SQ * 2 * 4);
  int*      tokIdx = (int*)alloc(2 * SQ * 4);
  float*    tokW   = (float*)alloc(2 * SQ * 4);
  int*      slotOf = (int*)alloc(2 * SQ * 4);
  int*      counts = (int*)alloc(256);
  int*      offsb  = (int*)alloc(256);
  int*      cursors= (int*)alloc(256);
  ushort_t* ffnH   = (ushort_t*)alloc((size_t)SQ * FFD * 2);      // ┐ moehid
  ushort_t* ffnL   = (ushort_t*)alloc((size_t)SQ * FFD * 2);      // ┘ 32MiB
  float*    eo     = (float*)alloc((size_t)2 * 2 * SQ * DM * 4);  // 32MiB (also KS partials)
  ushort_t* inwH[2], *inwL[2], *outwH[2], *outwL[2];
  ushort_t* wsplit0 = (ushort_t*)alloc(0);
  inwH[0]  = (ushort_t*)alloc((size_t)3 * DM * DM * 2);
  inwL[0]  = (ushort_t*)alloc((size_t)3 * DM * DM * 2);
  inwH[1]  = (ushort_t*)alloc((size_t)3 * DM * DM * 2);
  inwL[1]  = (ushort_t*)alloc((size_t)3 * DM * DM * 2);
  outwH[0] = (ushort_t*)alloc((size_t)DM * DM * 2);
  outwL[0] = (ushort_t*)alloc((size_t)DM * DM * 2);
  outwH[1] = (ushort_t*)alloc((size_t)DM * DM * 2);
  outwL[1] = (ushort_t*)alloc((size_t)DM * DM * 2);
  ushort_t* f1H = (ushort_t*)alloc((size_t)FFD * DM * 2);
  ushort_t* f1L = (ushort_t*)alloc((size_t)FFD * DM * 2);
  ushort_t* f2H = (ushort_t*)alloc((size_t)DM * FFD * 2);
  ushort_t* f2L = (ushort_t*)alloc((size_t)DM * FFD * 2);
  ushort_t* moe_w1b = wsplit0;            // 64 MiB over weight planes
  ushort_t* moe_w2b = qkvH;               // 64 MiB over qkv+Vt+resv
  ushort_t* moehid  = ffnH;               // 32 MiB over ffn planes
  float*    pp      = eo;                 // KS partial planes
  const long long eoPC = (long long)2 * SQ * DM;
  const long long ppPC = (long long)SQ * DM;
  ushort_t* hfin    = (ushort_t*)d_ws;
  bool wsBig = ws_size >= ((size_t)70 << 20);
  ushort_t* head_wb = (ushort_t*)((char*)d_ws + ((size_t)4 << 20));
  (void)resv;

  embed_kernel<<<SQ, 256, 0, stream>>>(ids, embed_w, pos_w, x, counts);
  cvt_split2<<<dim3(512, 2), 256, 0, stream>>>(
      in_w[0], inwH[0], inwL[0], in_w[1], inwH[1], inwL[1], 3 * DM * DM / 4);
  cvt_split2<<<dim3(512, 2), 256, 0, stream>>>(
      out_w[0], outwH[0], outwL[0], out_w[1], outwH[1], outwL[1], DM * DM / 4);
  cvt_split2<<<dim3(512, 2), 256, 0, stream>>>(
      ffn_w1, f1H, f1L, ffn_w2, f2H, f2L, FFD * DM / 4);
  if (wsBig)
    cvt_bf16<<<1024, 256, 0, stream>>>(head_w, head_wb, NVOC * DM / 4);

  // ---- Layer 0 ----
  ln_fused<0, 0><<<SQ, 256, 0, stream>>>(x, nullptr, 0, nullptr,
                                         ln1_g[0], ln1_b[0], hbufH, hbufL);
  k_qkv<<<dim3(16, 24, 1), 256, 0, stream>>>(
      hbufH, hbufL, DM, 0, inwH[0], inwL[0], DM, 0,
      nullptr, qkvH, qkvL, 3 * DM, 0, 0,
      SQ, 3 * DM, DM, in_b[0], 1.f, VtH, VtL);
  k_attn<<<dim3(SQ / 64, NH), 256, 0, stream>>>(qkvH, qkvL, VtH, VtL,
                                                attnH, attnL);
  k_outp<<<dim3(16, 16, 4), 256, 0, stream>>>(
      attnH, attnL, DM, 0, outwH[0], outwL[0], DM, 0,
      pp, nullptr, nullptr, DM, 0, ppPC,
      SQ, DM, DM / 4, nullptr, 1.f, nullptr, nullptr);
  ln_fused<0, 4><<<SQ, 256, 0, stream>>>(x, pp, ppPC, out_b[0],
                                         ln2_g[0], ln2_b[0], hbufH, hbufL);
  k_ffn1<<<dim3(16, 32, 1), 256, 0, stream>>>(
      hbufH, hbufL, DM, 0, f1H, f1L, DM, 0,
      nullptr, ffnH, ffnL, FFD, 0, 0,
      SQ, FFD, DM, ffn_b1, 1.f, nullptr, nullptr);
  k_ffn2<<<dim3(16, 16, 2), 256, 0, stream>>>(
      ffnH, ffnL, FFD, 0, f2H, f2L, FFD, 0,
      pp, nullptr, nullptr, DM, 0, ppPC,
      SQ, DM, FFD / 2, nullptr, 1.f, nullptr, nullptr);
  // ---- Layer 1 ----
  ln_fused<0, 2><<<SQ, 256, 0, stream>>>(x, pp, ppPC, ffn_b2,
                                         ln1_g[1], ln1_b[1], hbufH, hbufL);
  k_qkv<<<dim3(16, 24, 1), 256, 0, stream>>>(
      hbufH, hbufL, DM, 0, inwH[1], inwL[1], DM, 0,
      nullptr, qkvH, qkvL, 3 * DM, 0, 0,
      SQ, 3 * DM, DM, in_b[1], 1.f, VtH, VtL);
  k_attn<<<dim3(SQ / 64, NH), 256, 0, stream>>>(qkvH, qkvL, VtH, VtL,
                                                attnH, attnL);
  k_outp<<<dim3(16, 16, 4), 256, 0, stream>>>(
      attnH, attnL, DM, 0, outwH[1], outwL[1], DM, 0,
      pp, nullptr, nullptr, DM, 0, ppPC,
      SQ, DM, DM / 4, nullptr, 1.f, nullptr, nullptr);
  cvt_bf16_2<<<dim3(2048, 2), 256, 0, stream>>>(
      moe_w1, moe_w1b, moe_w2, moe_w2b, 8 * FFD * DM / 4);
  ln_gate_top2<<<SQ, 256, 0, stream>>>(x, pp, ppPC, out_b[1],
                                       ln2_g[1], ln2_b[1], gate_w, gate_b,
                                       topi, topw, counts, hbufH);
  moe_prefix<<<1, 64, 0, stream>>>(counts, offsb, cursors);
  moe_gather<<<SQ, 256, 0, stream>>>(hbufH, topi, topw, offsb, cursors,
                                     tokIdx, tokW, slotOf, Xg);
  k_moe1<<<dim3(32, 16, 8), 256, 0, stream>>>(
      Xg, DM, 0, moe_w1b, DM, (long long)FFD * DM,
      moehid, FFD, 0, 0, SQ, FFD, DM, moe_b1, FFD, offsb);
  k_moe2<<<dim3(8, 16, 16), 256, 0, stream>>>(
      moehid, FFD, 0, moe_w2b, FFD, (long long)DM * FFD,
      eo, DM, 0, eoPC, SQ, DM, FFD, nullptr, 0, offsb);
  moe_ln_final<<<SQ, 256, 0, stream>>>(x, eo, eoPC, slotOf, topi, topw,
                                       moe_b2, norm_g, norm_b, hfin);
  if (wsBig)
    k_head_bf<<<dim3(8, 250, 1), 256, 0, stream>>>(
        hfin, DM, 0, head_wb, DM, 0, d_out, NVOC, 0, 0,
        SQ, NVOC, DM, nullptr, 0, nullptr);
  else
    k_head_f<<<dim3(8, 250, 1), 256, 0, stream>>>(
        hfin, DM, 0, head_w, DM, 0, d_out, NVOC, 0, 0,
        SQ, NVOC, DM, nullptr, 0, nullptr);
}

// Round 21
// 1125.694 us; speedup vs baseline: 1.0049x; 1.0049x over previous
//
#include <hip/hip_runtime.h>
#include <hip/hip_bf16.h>
#include <math.h>

typedef unsigned short ushort_t;
typedef __attribute__((ext_vector_type(8))) __bf16 bf16x8;
typedef __attribute__((ext_vector_type(4))) float f32x4;
typedef __attribute__((ext_vector_type(8))) short s8v;
typedef __attribute__((ext_vector_type(4))) short s4v;

#define SQ 2048
#define DM 1024
#define NH 16
#define HDIM 64
#define FFD 4096
#define NVOC 32000

__device__ inline float b2f(unsigned short u) {
  union { unsigned int i; float f; } x; x.i = ((unsigned int)u) << 16; return x.f;
}
__device__ inline unsigned short f2b(float f) {
  __hip_bfloat16 h = __float2bfloat16(f);
  return *reinterpret_cast<unsigned short*>(&h);
}
__device__ inline void split2(float x, ushort_t& h, ushort_t& l) {
  h = f2b(x);
  l = f2b(x - b2f(h));
}
__device__ inline float geluf(float v) {
  return 0.5f * v * (1.0f + erff(v * 0.70710678118654752f));
}
__device__ __forceinline__ void gld16(const void* g, void* l) {
  __builtin_amdgcn_global_load_lds(
      (const __attribute__((address_space(1))) void*)g,
      (__attribute__((address_space(3))) void*)l, 16, 0, 0);
}
#define MFMA __builtin_amdgcn_mfma_f32_16x16x32_bf16

// ---------------------------------------------------------------------------
// Split GEMM engine (pre-gate math), 2-phase double-buffered.
// EPI: 2 f32 partial store (kc*pC), 4 gelu+bias split-store,
//      5 split-store+bias with V-region (n0>=2048) written TRANSPOSED to TH/TL.
// ---------------------------------------------------------------------------
template<int EPI, int NT, int KS>
__device__ __forceinline__ void gemmsp_body(
    const ushort_t* __restrict__ AH, const ushort_t* __restrict__ AL,
    int lda, long long bA,
    const ushort_t* __restrict__ BH, const ushort_t* __restrict__ BL,
    int ldb, long long bB,
    float* __restrict__ C, ushort_t* __restrict__ CH, ushort_t* __restrict__ CL,
    int ldc, long long bC, long long pC,
    int M, int N, int K, const float* __restrict__ bias, float alpha,
    ushort_t* __restrict__ TH, ushort_t* __restrict__ TL)
{
  int z = blockIdx.z, h = z / KS, kc = z % KS;
  const ushort_t* AHp = AH + (long long)h * bA + (long long)kc * K;
  const ushort_t* ALp = AL + (long long)h * bA + (long long)kc * K;
  const ushort_t* BHp = BH + (long long)h * bB + (long long)kc * K;
  const ushort_t* BLp = BL + (long long)h * bB + (long long)kc * K;
  int m0 = blockIdx.x * 128, n0 = blockIdx.y * NT;
  const int NF = NT / 32;

  __shared__ __align__(16) ushort_t sAH[2][128 * 32], sAL[2][128 * 32];
  __shared__ __align__(16) ushort_t sBH[2][NT * 32],  sBL[2][NT * 32];

  int tid = threadIdx.x, lane = tid & 63, wave = tid >> 6;
  int wr = (wave >> 1) * 64, wc = (wave & 1) * (NT >> 1);
  int l15 = lane & 15, l4 = lane >> 4;

  f32x4 acc[4][NF];
#pragma unroll
  for (int m = 0; m < 4; ++m)
#pragma unroll
    for (int n = 0; n < NF; ++n) acc[m][n] = (f32x4){0.f, 0.f, 0.f, 0.f};

  auto stageG = [&](int buf, int k0) {
#pragma unroll
    for (int i = 0; i < 2; ++i) {
      int fi = i * 2048 + tid * 8;
      int r = fi >> 5, chk = (fi >> 3) & 3;
      int scol = ((chk ^ ((r >> 1) & 3)) << 3);
      int ra = m0 + r; if (ra > M - 1) ra = M - 1;
      long long go = (long long)ra * lda + k0 + scol;
      gld16(AHp + go, &sAH[buf][fi]);
      gld16(ALp + go, &sAL[buf][fi]);
    }
#pragma unroll
    for (int i = 0; i < NT / 64; ++i) {
      int fi = i * 2048 + tid * 8;
      int r = fi >> 5, chk = (fi >> 3) & 3;
      int scol = ((chk ^ ((r >> 1) & 3)) << 3);
      int rb = n0 + r; if (rb > N - 1) rb = N - 1;
      long long go = (long long)rb * ldb + k0 + scol;
      gld16(BHp + go, &sBH[buf][fi]);
      gld16(BLp + go, &sBL[buf][fi]);
    }
  };

  int nIt = K >> 5;
  stageG(0, 0);
  for (int it = 0; it < nIt; ++it) {
    int cur = it & 1;
    __syncthreads();
    if (it + 1 < nIt) stageG(cur ^ 1, (it + 1) << 5);
    bf16x8 ah[4], al[4], bh[NF], bl[NF];
#pragma unroll
    for (int m = 0; m < 4; ++m) {
      int r = wr + m * 16 + l15;
      int o = r * 32 + ((l4 ^ ((r >> 1) & 3)) << 3);
      ah[m] = *(const bf16x8*)&sAH[cur][o];
      al[m] = *(const bf16x8*)&sAL[cur][o];
    }
#pragma unroll
    for (int n = 0; n < NF; ++n) {
      int r = wc + n * 16 + l15;
      int o = r * 32 + ((l4 ^ ((r >> 1) & 3)) << 3);
      bh[n] = *(const bf16x8*)&sBH[cur][o];
      bl[n] = *(const bf16x8*)&sBL[cur][o];
    }
#pragma unroll
    for (int m = 0; m < 4; ++m)
#pragma unroll
      for (int n = 0; n < NF; ++n) {
        acc[m][n] = MFMA(ah[m], bh[n], acc[m][n], 0, 0, 0);
        acc[m][n] = MFMA(al[m], bh[n], acc[m][n], 0, 0, 0);
        acc[m][n] = MFMA(ah[m], bl[n], acc[m][n], 0, 0, 0);
      }
  }

  if (EPI == 5 && n0 >= 2 * DM) {
#pragma unroll
    for (int m = 0; m < 4; ++m) {
      int rbase = m0 + wr + m * 16 + l4 * 4;
#pragma unroll
      for (int n = 0; n < NF; ++n) {
        int c = n0 + wc + n * 16 + l15;
        int d = c - 2 * DM;
        float bv = bias[c];
        s4v hv, lv;
#pragma unroll
        for (int q = 0; q < 4; ++q) {
          ushort_t hh, ll; split2(acc[m][n][q] + bv, hh, ll);
          hv[q] = (short)hh; lv[q] = (short)ll;
        }
        *(s4v*)&TH[(long long)d * SQ + rbase] = hv;
        *(s4v*)&TL[(long long)d * SQ + rbase] = lv;
      }
    }
    return;
  }

#pragma unroll
  for (int m = 0; m < 4; ++m) {
#pragma unroll
    for (int n = 0; n < NF; ++n) {
      int c = n0 + wc + n * 16 + l15;
      if (c >= N) continue;
      float bv = (EPI == 4 || EPI == 5) ? bias[c] : 0.f;
#pragma unroll
      for (int q = 0; q < 4; ++q) {
        int rr = m0 + wr + m * 16 + l4 * 4 + q;
        if (rr >= M) continue;
        float v = acc[m][n][q];
        if (EPI == 5) {
          ushort_t hh, ll; split2(v + bv, hh, ll);
          long long o = (long long)rr * ldc + c; CH[o] = hh; CL[o] = ll;
        } else if (EPI == 2) {
          C[(long long)kc * pC + (long long)rr * ldc + (long long)h * bC + c] = v;
        } else if (EPI == 4) {
          ushort_t hh, ll; split2(geluf(v + bv), hh, ll);
          long long o = (long long)rr * ldc + c; CH[o] = hh; CL[o] = ll;
        }
      }
    }
  }
}

#define SP_ARGS const ushort_t* AH, const ushort_t* AL, int lda, long long bA, \
    const ushort_t* BH, const ushort_t* BL, int ldb, long long bB, \
    float* C, ushort_t* CH, ushort_t* CL, int ldc, long long bC, long long pC, \
    int M, int N, int K, const float* bias, float alpha, \
    ushort_t* TH, ushort_t* TL
#define SP_PASS AH, AL, lda, bA, BH, BL, ldb, bB, C, CH, CL, ldc, bC, pC, M, N, K, bias, alpha, TH, TL

__global__ __launch_bounds__(256) void k_qkv (SP_ARGS) { gemmsp_body<5,128,1>(SP_PASS); }
__global__ __launch_bounds__(256) void k_outp(SP_ARGS) { gemmsp_body<2, 64,4>(SP_PASS); }
__global__ __launch_bounds__(256) void k_ffn1(SP_ARGS) { gemmsp_body<4,128,1>(SP_PASS); }
__global__ __launch_bounds__(256) void k_ffn2(SP_ARGS) { gemmsp_body<2, 64,2>(SP_PASS); }

// ---------------------------------------------------------------------------
// Fused flash attention, split-f32 precision. Grid (32,16). K/V dbuf.
// ---------------------------------------------------------------------------
__global__ __launch_bounds__(256)
void k_attn(const ushort_t* __restrict__ qkvH, const ushort_t* __restrict__ qkvL,
            const ushort_t* __restrict__ VtH, const ushort_t* __restrict__ VtL,
            ushort_t* __restrict__ aH, ushort_t* __restrict__ aL)
{
  int f = blockIdx.x + blockIdx.y * gridDim.x;
  int logical = (f & 7) * 64 + (f >> 3);
  int q0 = (logical & 31) * 64;
  int h  = logical >> 5;

  __shared__ __align__(16) ushort_t sKH[2][4096], sKL[2][4096];
  __shared__ __align__(16) ushort_t sVH[2][4096], sVL[2][4096];
  __shared__ __align__(16) ushort_t sPH[4096], sPL[4096];

  int tid = threadIdx.x, lane = tid & 63, wave = tid >> 6;
  int l15 = lane & 15, l4 = lane >> 4;

  bf16x8 qh[2], ql[2];
  {
    long long base = (long long)(q0 + wave * 16 + l15) * (3 * DM) + h * 64 + l4 * 8;
    qh[0] = *(const bf16x8*)(qkvH + base);
    qh[1] = *(const bf16x8*)(qkvH + base + 32);
    ql[0] = *(const bf16x8*)(qkvL + base);
    ql[1] = *(const bf16x8*)(qkvL + base + 32);
  }

  auto stageKV = [&](int buf, int kt) {
#pragma unroll
    for (int i = 0; i < 2; ++i) {
      int idx = i * 2048 + tid * 8;
      int row = idx >> 6, chk = (idx >> 3) & 7;
      int scol = ((chk ^ (row & 7)) << 3);
      long long gk = (long long)(kt * 64 + row) * (3 * DM) + DM + h * 64 + scol;
      long long gv = (long long)(h * 64 + row) * SQ + kt * 64 + scol;
      gld16(qkvH + gk, &sKH[buf][idx]);
      gld16(qkvL + gk, &sKL[buf][idx]);
      gld16(VtH + gv, &sVH[buf][idx]);
      gld16(VtL + gv, &sVL[buf][idx]);
    }
  };

  float mrow[4], lrow[4];
  f32x4 Oacc[4];
#pragma unroll
  for (int r = 0; r < 4; ++r) { mrow[r] = -1e30f; lrow[r] = 0.f; }
#pragma unroll
  for (int n = 0; n < 4; ++n) Oacc[n] = (f32x4){0.f, 0.f, 0.f, 0.f};

  const int NT = SQ / 64;
  stageKV(0, 0);
  for (int kt = 0; kt < NT; ++kt) {
    int cur = kt & 1;
    __syncthreads();
    if (kt + 1 < NT) stageKV(cur ^ 1, kt + 1);

    f32x4 S[4];
#pragma unroll
    for (int n = 0; n < 4; ++n) S[n] = (f32x4){0.f, 0.f, 0.f, 0.f};
#pragma unroll
    for (int kk = 0; kk < 64; kk += 32) {
      int kkI = kk >> 5;
      bf16x8 qhf = qh[kkI], qlf = ql[kkI];
#pragma unroll
      for (int n = 0; n < 4; ++n) {
        int br = n * 16 + l15;
        int bo = br * 64 + ((((kk >> 3) + l4) ^ (br & 7)) << 3);
        bf16x8 kh = *(const bf16x8*)&sKH[cur][bo];
        bf16x8 kl = *(const bf16x8*)&sKL[cur][bo];
        S[n] = MFMA(qhf, kh, S[n], 0, 0, 0);
        S[n] = MFMA(qlf, kh, S[n], 0, 0, 0);
        S[n] = MFMA(qhf, kl, S[n], 0, 0, 0);
      }
    }
    float tm[4], ts[4];
#pragma unroll
    for (int r = 0; r < 4; ++r) {
#pragma unroll
      for (int n = 0; n < 4; ++n) S[n][r] *= 0.125f;
      tm[r] = fmaxf(fmaxf(S[0][r], S[1][r]), fmaxf(S[2][r], S[3][r]));
    }
#pragma unroll
    for (int mk = 1; mk <= 8; mk <<= 1)
#pragma unroll
      for (int r = 0; r < 4; ++r) tm[r] = fmaxf(tm[r], __shfl_xor(tm[r], mk));
#pragma unroll
    for (int r = 0; r < 4; ++r) {
      float mn = fmaxf(mrow[r], tm[r]);
      float corr = __expf(mrow[r] - mn);
      mrow[r] = mn;
      float s = 0.f;
#pragma unroll
      for (int n = 0; n < 4; ++n) { S[n][r] = __expf(S[n][r] - mn); s += S[n][r]; }
      ts[r] = s;
      lrow[r] *= corr;
#pragma unroll
      for (int n = 0; n < 4; ++n) Oacc[n][r] *= corr;
    }
#pragma unroll
    for (int mk = 1; mk <= 8; mk <<= 1)
#pragma unroll
      for (int r = 0; r < 4; ++r) ts[r] += __shfl_xor(ts[r], mk);
#pragma unroll
    for (int r = 0; r < 4; ++r) lrow[r] += ts[r];

    {
      ushort_t* pH = &sPH[wave * 1024];
      ushort_t* pL = &sPL[wave * 1024];
#pragma unroll
      for (int n = 0; n < 4; ++n)
#pragma unroll
        for (int r = 0; r < 4; ++r) {
          int row = l4 * 4 + r, col = n * 16 + l15;
          int ad = row * 64 + (((col >> 3) ^ (row & 7)) << 3) + (col & 7);
          ushort_t hh, ll; split2(S[n][r], hh, ll);
          pH[ad] = hh; pL[ad] = ll;
        }
    }
    __syncthreads();
#pragma unroll
    for (int kk = 0; kk < 64; kk += 32) {
      int ao = wave * 1024 + l15 * 64 + ((((kk >> 3) + l4) ^ (l15 & 7)) << 3);
      bf16x8 ph = *(const bf16x8*)&sPH[ao];
      bf16x8 pl = *(const bf16x8*)&sPL[ao];
#pragma unroll
      for (int n = 0; n < 4; ++n) {
        int br = n * 16 + l15;
        int bo = br * 64 + ((((kk >> 3) + l4) ^ (br & 7)) << 3);
        bf16x8 vh = *(const bf16x8*)&sVH[cur][bo];
        bf16x8 vl = *(const bf16x8*)&sVL[cur][bo];
        Oacc[n] = MFMA(ph, vh, Oacc[n], 0, 0, 0);
        Oacc[n] = MFMA(pl, vh, Oacc[n], 0, 0, 0);
        Oacc[n] = MFMA(ph, vl, Oacc[n], 0, 0, 0);
      }
    }
  }

#pragma unroll
  for (int n = 0; n < 4; ++n)
#pragma unroll
    for (int r = 0; r < 4; ++r) {
      int q = q0 + wave * 16 + l4 * 4 + r;
      int d = h * 64 + n * 16 + l15;
      float val = Oacc[n][r] / lrow[r];
      ushort_t hh, ll; split2(val, hh, ll);
      long long o = (long long)q * DM + d;
      aH[o] = hh; aL[o] = ll;
    }
}

// ---------------------------------------------------------------------------
// bf16 GEMM engine "s" (MoE): BM=128, BK=32, 32KB LDS -> 5 blocks/CU (r15).
// EPI: 2 gelu(+bias) bf16 store, 7 f32 partial store via LDS-transpose.
// ---------------------------------------------------------------------------
template<int EPI, int SWAP, int KS>
__device__ __forceinline__ void gemm16s_body(
    const ushort_t* __restrict__ A, int lda, long long bA,
    const ushort_t* __restrict__ Bp0, int ldb, long long bB,
    void* __restrict__ Cv, int ldc, long long bC, long long pC,
    int M, int N, int K, const float* __restrict__ bias, int bBias,
    const int* __restrict__ offs)
{
  int bz = blockIdx.z;
  int z = bz / KS, kc = bz % KS;
  int Kc = K / KS;
  const ushort_t* Ap = A + (long long)z * bA + (long long)kc * Kc;
  const ushort_t* Bp = Bp0 + (long long)z * bB + (long long)kc * Kc;
  int rowStart = 0, Meff = M;
  if (offs) { rowStart = offs[z]; Meff = offs[z + 1] - rowStart; }
  int m0 = (SWAP ? blockIdx.y : blockIdx.x) * 128;
  if (m0 >= Meff) return;
  int n0 = (SWAP ? blockIdx.x : blockIdx.y) * 128;

  __shared__ __align__(16) char smem[32768];

  int tid = threadIdx.x, lane = tid & 63, wave = tid >> 6;
  int wr = (wave >> 1) * 64, wc = (wave & 1) * 64;
  int l15 = lane & 15, l4 = lane >> 4;

  f32x4 acc[4][4];
#pragma unroll
  for (int m = 0; m < 4; ++m)
#pragma unroll
    for (int n = 0; n < 4; ++n) acc[m][n] = (f32x4){0.f, 0.f, 0.f, 0.f};

  auto stageG = [&](int buf, int k0) {
    ushort_t* dA = (ushort_t*)(smem + buf * 8192);
    ushort_t* dB = (ushort_t*)(smem + 16384 + buf * 8192);
#pragma unroll
    for (int i = 0; i < 2; ++i) {
      int idx = i * 2048 + tid * 8;
      int row = idx >> 5, chk = (idx >> 3) & 3;
      int scol = ((chk ^ ((row >> 1) & 3)) << 3);
      int ra = m0 + row; if (ra > Meff - 1) ra = Meff - 1;
      gld16(Ap + (long long)(rowStart + ra) * lda + k0 + scol, &dA[idx]);
    }
#pragma unroll
    for (int i = 0; i < 2; ++i) {
      int idx = i * 2048 + tid * 8;
      int row = idx >> 5, chk = (idx >> 3) & 3;
      int scol = ((chk ^ ((row >> 1) & 3)) << 3);
      int rb = n0 + row; if (rb > N - 1) rb = N - 1;
      gld16(Bp + (long long)rb * ldb + k0 + scol, &dB[idx]);
    }
  };

  int nIt = Kc >> 5;
  stageG(0, 0);
  for (int it = 0; it < nIt; ++it) {
    int cur = it & 1;
    __syncthreads();
    if (it + 1 < nIt) stageG(cur ^ 1, (it + 1) << 5);
    ushort_t* As = (ushort_t*)(smem + cur * 8192);
    ushort_t* Bs = (ushort_t*)(smem + 16384 + cur * 8192);
    bf16x8 af[4], bfr[4];
#pragma unroll
    for (int m = 0; m < 4; ++m) {
      int r = wr + m * 16 + l15;
      af[m] = *(const bf16x8*)&As[r * 32 + ((l4 ^ ((r >> 1) & 3)) << 3)];
    }
#pragma unroll
    for (int n = 0; n < 4; ++n) {
      int r = wc + n * 16 + l15;
      bfr[n] = *(const bf16x8*)&Bs[r * 32 + ((l4 ^ ((r >> 1) & 3)) << 3)];
    }
#pragma unroll
    for (int m = 0; m < 4; ++m)
#pragma unroll
      for (int n = 0; n < 4; ++n)
        acc[m][n] = MFMA(af[m], bfr[n], acc[m][n], 0, 0, 0);
  }
  __syncthreads();

  if (EPI == 7) {
    float* fE = (float*)smem;
#pragma unroll
    for (int h2 = 0; h2 < 2; ++h2) {
      if ((wave >> 1) == h2) {
#pragma unroll
        for (int m = 0; m < 4; ++m)
#pragma unroll
          for (int n = 0; n < 4; ++n)
#pragma unroll
            for (int q = 0; q < 4; ++q)
              fE[(m * 16 + l4 * 4 + q) * 128 + wc + n * 16 + l15] = acc[m][n][q];
      }
      __syncthreads();
#pragma unroll
      for (int i = 0; i < 8; ++i) {
        int lin = tid + i * 256;
        int row = lin >> 5, c4 = (lin & 31) << 2;
        int gr = m0 + h2 * 64 + row;
        if (gr < Meff) {
          f32x4 v4 = *(const f32x4*)&fE[row * 128 + c4];
          long long crow = rowStart + gr;
          float* dst = (float*)Cv + (long long)kc * pC + crow * ldc + n0 + c4;
          *(f32x4*)dst = v4;
        }
      }
      __syncthreads();
    }
    return;
  }

#pragma unroll
  for (int m = 0; m < 4; ++m) {
#pragma unroll
    for (int n = 0; n < 4; ++n) {
      int c = n0 + wc + n * 16 + l15;
      if (c >= N) continue;
      float bv = (EPI == 2) ? bias[(long long)z * bBias + c] : 0.f;
#pragma unroll
      for (int q = 0; q < 4; ++q) {
        int rr = m0 + wr + m * 16 + l4 * 4 + q;
        if (rr >= Meff) continue;
        float v = acc[m][n][q];
        long long crow = rowStart + rr;
        if (EPI == 2)
          ((ushort_t*)Cv)[crow * ldc + (long long)z * bC + c] = f2b(geluf(v + bv));
      }
    }
  }
}

// ---------------------------------------------------------------------------
// bf16 GEMM engine "w" (head): BM=256 x BN=128, BK=32, wave tile 128x64.
// Per K-step 32 MFMA vs 12 ds_read -> MFMA-bound. LDS 48KB.
// ---------------------------------------------------------------------------
template<int BSRC>
__device__ __forceinline__ void gemm16w_body(
    const ushort_t* __restrict__ A, int lda,
    const void* __restrict__ Bv, int ldb,
    float* __restrict__ Cv, int ldc,
    int M, int N, int K)
{
  int bx = blockIdx.x, by = blockIdx.y;
  {
    int flat = bx + by * gridDim.x;
    int cpx = (gridDim.x * gridDim.y) >> 3;
    int s = (flat & 7) * cpx + (flat >> 3);
    bx = s % gridDim.x; by = s / gridDim.x;
  }
  int m0 = bx * 256;
  int n0 = by * 128;

  __shared__ __align__(16) char smem[49152];
  const ushort_t* Bp = (BSRC == 1) ? (const ushort_t*)Bv : nullptr;
  const float* Bf = (BSRC == 0) ? (const float*)Bv : nullptr;

  int tid = threadIdx.x, lane = tid & 63, wave = tid >> 6;
  int wr = (wave >> 1) * 128, wc = (wave & 1) * 64;
  int l15 = lane & 15, l4 = lane >> 4;

  f32x4 acc[8][4];
#pragma unroll
  for (int m = 0; m < 8; ++m)
#pragma unroll
    for (int n = 0; n < 4; ++n) acc[m][n] = (f32x4){0.f, 0.f, 0.f, 0.f};

  auto stageG = [&](int buf, int k0) {
    ushort_t* dA = (ushort_t*)(smem + buf * 16384);
    ushort_t* dB = (ushort_t*)(smem + 32768 + buf * 8192);
#pragma unroll
    for (int i = 0; i < 4; ++i) {
      int idx = i * 2048 + tid * 8;
      int row = idx >> 5, chk = (idx >> 3) & 3;
      int scol = ((chk ^ ((row >> 1) & 3)) << 3);
      int ra = m0 + row; if (ra > M - 1) ra = M - 1;
      gld16(A + (long long)ra * lda + k0 + scol, &dA[idx]);
    }
    if (BSRC == 1) {
#pragma unroll
      for (int i = 0; i < 2; ++i) {
        int idx = i * 2048 + tid * 8;
        int row = idx >> 5, chk = (idx >> 3) & 3;
        int scol = ((chk ^ ((row >> 1) & 3)) << 3);
        int rb = n0 + row; if (rb > N - 1) rb = N - 1;
        gld16(Bp + (long long)rb * ldb + k0 + scol, &dB[idx]);
      }
    } else {
#pragma unroll
      for (int i = 0; i < 4; ++i) {
        int g = tid + i * 256;
        int r = g >> 3, c4 = (g & 7) * 4;
        int rb = n0 + r; if (rb > N - 1) rb = N - 1;
        float4 fv = *(const float4*)(Bf + (long long)rb * ldb + k0 + c4);
        s4v o; o[0] = (short)f2b(fv.x); o[1] = (short)f2b(fv.y);
        o[2] = (short)f2b(fv.z); o[3] = (short)f2b(fv.w);
        int dst = r * 32 + ((((c4 >> 3) ^ ((r >> 1) & 3))) << 3) + (c4 & 7);
        *(s4v*)&dB[dst] = o;
      }
    }
  };

  int nIt = K >> 5;
  stageG(0, 0);
  for (int it = 0; it < nIt; ++it) {
    int cur = it & 1;
    __syncthreads();
    if (it + 1 < nIt) stageG(cur ^ 1, (it + 1) << 5);
    ushort_t* As = (ushort_t*)(smem + cur * 16384);
    ushort_t* Bs = (ushort_t*)(smem + 32768 + cur * 8192);
    bf16x8 af[8], bfr[4];
#pragma unroll
    for (int m = 0; m < 8; ++m) {
      int r = wr + m * 16 + l15;
      af[m] = *(const bf16x8*)&As[r * 32 + ((l4 ^ ((r >> 1) & 3)) << 3)];
    }
#pragma unroll
    for (int n = 0; n < 4; ++n) {
      int r = wc + n * 16 + l15;
      bfr[n] = *(const bf16x8*)&Bs[r * 32 + ((l4 ^ ((r >> 1) & 3)) << 3)];
    }
#pragma unroll
    for (int m = 0; m < 8; ++m)
#pragma unroll
      for (int n = 0; n < 4; ++n)
        acc[m][n] = MFMA(af[m], bfr[n], acc[m][n], 0, 0, 0);
  }
  __syncthreads();

  // LDS-transpose epilogue: 4 passes of 64x128 f32, non-temporal float4 stores
  float* fE = (float*)smem;
#pragma unroll
  for (int h2 = 0; h2 < 4; ++h2) {
    if ((wave >> 1) == (h2 >> 1)) {
#pragma unroll
      for (int mm = 0; mm < 4; ++mm) {
        int m = (h2 & 1) * 4 + mm;
#pragma unroll
        for (int n = 0; n < 4; ++n)
#pragma unroll
          for (int q = 0; q < 4; ++q)
            fE[(mm * 16 + l4 * 4 + q) * 128 + wc + n * 16 + l15] = acc[m][n][q];
      }
    }
    __syncthreads();
#pragma unroll
    for (int i = 0; i < 8; ++i) {
      int lin = tid + i * 256;
      int row = lin >> 5, c4 = (lin & 31) << 2;
      int gr = m0 + h2 * 64 + row;
      if (gr < M) {
        f32x4 v4 = *(const f32x4*)&fE[row * 128 + c4];
        float* dst = Cv + (long long)gr * ldc + n0 + c4;
        __builtin_nontemporal_store(v4, (f32x4*)dst);
      }
    }
    __syncthreads();
  }
}

#define G16_ARGS const ushort_t* A, int lda, long long bA, const void* Bv, \
    int ldb, long long bB, void* Cv, int ldc, long long bC, long long pC, \
    int M, int N, int K, const float* bias, int bBias, const int* offs
#define G16S_PASS(EPI,SWAP,KS) gemm16s_body<EPI,SWAP,KS>(A, lda, bA, \
    (const ushort_t*)Bv, ldb, bB, Cv, ldc, bC, pC, M, N, K, bias, bBias, offs)

__global__ __launch_bounds__(256) void k_moe1(G16_ARGS) { G16S_PASS(2,1,1); }
__global__ __launch_bounds__(256) void k_moe2(G16_ARGS) { G16S_PASS(7,1,2); }
__global__ __launch_bounds__(256) void k_head_bf(G16_ARGS) {
  gemm16w_body<1>(A, lda, Bv, ldb, (float*)Cv, ldc, M, N, K);
}
__global__ __launch_bounds__(256) void k_head_f(G16_ARGS) {
  gemm16w_body<0>(A, lda, Bv, ldb, (float*)Cv, ldc, M, N, K);
}

// ---------------------------------------------------------------------------
__global__ __launch_bounds__(256)
void cvt_split2(const float* __restrict__ s0, ushort_t* __restrict__ dh0,
                ushort_t* __restrict__ dl0,
                const float* __restrict__ s1, ushort_t* __restrict__ dh1,
                ushort_t* __restrict__ dl1, int n4)
{
  const float* s = blockIdx.y ? s1 : s0;
  ushort_t* dh = blockIdx.y ? dh1 : dh0;
  ushort_t* dl = blockIdx.y ? dl1 : dl0;
  int i = blockIdx.x * blockDim.x + threadIdx.x;
  int stride = gridDim.x * blockDim.x;
  for (; i < n4; i += stride) {
    float4 f = ((const float4*)s)[i];
    s4v h, l; ushort_t hh, ll;
    split2(f.x, hh, ll); h[0] = (short)hh; l[0] = (short)ll;
    split2(f.y, hh, ll); h[1] = (short)hh; l[1] = (short)ll;
    split2(f.z, hh, ll); h[2] = (short)hh; l[2] = (short)ll;
    split2(f.w, hh, ll); h[3] = (short)hh; l[3] = (short)ll;
    ((s4v*)dh)[i] = h; ((s4v*)dl)[i] = l;
  }
}

__global__ __launch_bounds__(256)
void cvt_bf16(const float* __restrict__ s, ushort_t* __restrict__ d, int n4)
{
  int i = blockIdx.x * blockDim.x + threadIdx.x;
  int stride = gridDim.x * blockDim.x;
  for (; i < n4; i += stride) {
    float4 f = ((const float4*)s)[i];
    s4v o; o[0] = (short)f2b(f.x); o[1] = (short)f2b(f.y);
    o[2] = (short)f2b(f.z); o[3] = (short)f2b(f.w);
    ((s4v*)d)[i] = o;
  }
}

__global__ __launch_bounds__(256)
void cvt_bf16_2(const float* __restrict__ s0, ushort_t* __restrict__ d0,
                const float* __restrict__ s1, ushort_t* __restrict__ d1, int n4)
{
  const float* s = blockIdx.y ? s1 : s0;
  ushort_t* d = blockIdx.y ? d1 : d0;
  int i = blockIdx.x * blockDim.x + threadIdx.x;
  int stride = gridDim.x * blockDim.x;
  for (; i < n4; i += stride) {
    float4 f = ((const float4*)s)[i];
    s4v o; o[0] = (short)f2b(f.x); o[1] = (short)f2b(f.y);
    o[2] = (short)f2b(f.z); o[3] = (short)f2b(f.w);
    ((s4v*)d)[i] = o;
  }
}

__global__ __launch_bounds__(256)
void embed_kernel(const int* __restrict__ ids, const float* __restrict__ ew,
                  const float* __restrict__ pw, float* __restrict__ x,
                  int* __restrict__ counts)
{
  int srow = blockIdx.x, tid = threadIdx.x;
  if (srow == 0 && tid < 8) counts[tid] = 0;
  int id = ids[srow];
  const float4 e = *(const float4*)(ew + (long long)id * DM + tid * 4);
  const float4 p = *(const float4*)(pw + (long long)srow * DM + tid * 4);
  float4* xr = (float4*)(x + (long long)srow * DM) + tid;
  *xr = make_float4(e.x + p.x, e.y + p.y, e.z + p.z, e.w + p.w);
}

template<int MODE, int NP>
__global__ __launch_bounds__(256)
void ln_fused(float* __restrict__ x, const float* __restrict__ P, long long pC,
              const float* __restrict__ bias_pre,
              const float* __restrict__ g, const float* __restrict__ b,
              ushort_t* __restrict__ outH, ushort_t* __restrict__ outL)
{
  int row = blockIdx.x, tid = threadIdx.x;
  long long xo = (long long)row * DM + tid * 4;
  float4 v = *(const float4*)(x + xo);
  if (NP > 0) {
    float4 bp = *(const float4*)(bias_pre + tid * 4);
    float sx = bp.x, sy = bp.y, sz = bp.z, sw = bp.w;
#pragma unroll
    for (int p = 0; p < NP; ++p) {
      float4 pv = *(const float4*)(P + (long long)p * pC + xo);
      sx += pv.x; sy += pv.y; sz += pv.z; sw += pv.w;
    }
    v.x += sx; v.y += sy; v.z += sz; v.w += sw;
    *(float4*)(x + xo) = v;
  }
  __shared__ float sm1[4], sm2[4];
  float s = v.x + v.y + v.z + v.w;
  for (int o = 32; o > 0; o >>= 1) s += __shfl_down(s, o);
  if ((tid & 63) == 0) sm1[tid >> 6] = s;
  __syncthreads();
  float mean = (sm1[0] + sm1[1] + sm1[2] + sm1[3]) * (1.0f / DM);
  float d0 = v.x - mean, d1 = v.y - mean, d2 = v.z - mean, d3 = v.w - mean;
  float q = d0 * d0 + d1 * d1 + d2 * d2 + d3 * d3;
  for (int o = 32; o > 0; o >>= 1) q += __shfl_down(q, o);
  if ((tid & 63) == 0) sm2[tid >> 6] = q;
  __syncthreads();
  float var = (sm2[0] + sm2[1] + sm2[2] + sm2[3]) * (1.0f / DM);
  float rstd = rsqrtf(var + 1e-5f);
  float4 gv = ((const float4*)g)[tid];
  float4 bv = ((const float4*)b)[tid];
  float o0 = d0 * rstd * gv.x + bv.x, o1 = d1 * rstd * gv.y + bv.y;
  float o2 = d2 * rstd * gv.z + bv.z, o3 = d3 * rstd * gv.w + bv.w;
  long long base = (long long)row * DM + tid * 4;
  if (MODE == 0) {
    ushort_t hh, ll;
    split2(o0, hh, ll); outH[base + 0] = hh; outL[base + 0] = ll;
    split2(o1, hh, ll); outH[base + 1] = hh; outL[base + 1] = ll;
    split2(o2, hh, ll); outH[base + 2] = hh; outL[base + 2] = ll;
    split2(o3, hh, ll); outH[base + 3] = hh; outL[base + 3] = ll;
  } else {
    outH[base + 0] = f2b(o0); outH[base + 1] = f2b(o1);
    outH[base + 2] = f2b(o2); outH[base + 3] = f2b(o3);
  }
}

__global__ __launch_bounds__(256)
void ln_gate_top2(float* __restrict__ x, const float* __restrict__ P,
                  long long pC, const float* __restrict__ bias_pre,
                  const float* __restrict__ g, const float* __restrict__ b,
                  const float* __restrict__ gw, const float* __restrict__ gb,
                  int* __restrict__ topi, float* __restrict__ topw,
                  int* __restrict__ counts, ushort_t* __restrict__ outH)
{
  int row = blockIdx.x, tid = threadIdx.x;
  long long xo = (long long)row * DM + tid * 4;
  float4 v = *(const float4*)(x + xo);
  {
    float4 bp = *(const float4*)(bias_pre + tid * 4);
    float sx = bp.x, sy = bp.y, sz = bp.z, sw = bp.w;
#pragma unroll
    for (int p = 0; p < 4; ++p) {
      float4 pv = *(const float4*)(P + (long long)p * pC + xo);
      sx += pv.x; sy += pv.y; sz += pv.z; sw += pv.w;
    }
    v.x += sx; v.y += sy; v.z += sz; v.w += sw;
    *(float4*)(x + xo) = v;
  }
  __shared__ float sm1[4], sm2[4];
  __shared__ float se[8][4];
  float s = v.x + v.y + v.z + v.w;
  for (int o = 32; o > 0; o >>= 1) s += __shfl_down(s, o);
  if ((tid & 63) == 0) sm1[tid >> 6] = s;
  __syncthreads();
  float mean = (sm1[0] + sm1[1] + sm1[2] + sm1[3]) * (1.0f / DM);
  float d0 = v.x - mean, d1 = v.y - mean, d2 = v.z - mean, d3 = v.w - mean;
  float q = d0 * d0 + d1 * d1 + d2 * d2 + d3 * d3;
  for (int o = 32; o > 0; o >>= 1) q += __shfl_down(q, o);
  if ((tid & 63) == 0) sm2[tid >> 6] = q;
  __syncthreads();
  float var = (sm2[0] + sm2[1] + sm2[2] + sm2[3]) * (1.0f / DM);
  float rstd = rsqrtf(var + 1e-5f);
  float4 gv = ((const float4*)g)[tid];
  float4 bv = ((const float4*)b)[tid];
  float h0 = d0 * rstd * gv.x + bv.x, h1 = d1 * rstd * gv.y + bv.y;
  float h2 = d2 * rstd * gv.z + bv.z, h3 = d3 * rstd * gv.w + bv.w;
  long long base = (long long)row * DM + tid * 4;
  outH[base + 0] = f2b(h0); outH[base + 1] = f2b(h1);
  outH[base + 2] = f2b(h2); outH[base + 3] = f2b(h3);
#pragma unroll
  for (int e = 0; e < 8; ++e) {
    float4 w = ((const float4*)(gw + (long long)e * DM))[tid];
    float p = h0 * w.x + h1 * w.y + h2 * w.z + h3 * w.w;
    for (int o = 32; o > 0; o >>= 1) p += __shfl_down(p, o);
    if ((tid & 63) == 0) se[e][tid >> 6] = p;
  }
  __syncthreads();
  if (tid == 0) {
    float sc[8];
#pragma unroll
    for (int e = 0; e < 8; ++e)
      sc[e] = se[e][0] + se[e][1] + se[e][2] + se[e][3] + gb[e];
    int i1 = 0; float m1 = sc[0];
    for (int e = 1; e < 8; ++e) if (sc[e] > m1) { m1 = sc[e]; i1 = e; }
    int i2 = -1; float m2 = -1e30f;
    for (int e = 0; e < 8; ++e) if (e != i1 && sc[e] > m2) { m2 = sc[e]; i2 = e; }
    float e2 = __expf(m2 - m1);
    float w1 = 1.f / (1.f + e2);
    topi[row * 2] = i1; topi[row * 2 + 1] = i2;
    topw[row * 2] = w1; topw[row * 2 + 1] = 1.f - w1;
    atomicAdd(&counts[i1], 1);
    atomicAdd(&counts[i2], 1);
  }
}

__global__ void moe_prefix(const int* __restrict__ counts, int* __restrict__ offs,
                           int* __restrict__ cursors)
{
  if (threadIdx.x == 0 && blockIdx.x == 0) {
    int a = 0;
    for (int e = 0; e < 8; ++e) { offs[e] = a; a += counts[e]; cursors[e] = 0; }
    offs[8] = a;
  }
}

__global__ __launch_bounds__(256)
void moe_gather(const ushort_t* __restrict__ hH, const int* __restrict__ topi,
                const float* __restrict__ topw, const int* __restrict__ offs,
                int* __restrict__ cursors, int* __restrict__ tokIdx,
                float* __restrict__ tokW, int* __restrict__ slotOf,
                ushort_t* __restrict__ Xg)
{
  int tok = blockIdx.x, tid = threadIdx.x;
  __shared__ int s0s, s1s;
  if (tid == 0) {
    int e0 = topi[tok * 2], e1 = topi[tok * 2 + 1];
    int s0 = offs[e0] + atomicAdd(&cursors[e0], 1);
    int s1 = offs[e1] + atomicAdd(&cursors[e1], 1);
    tokIdx[s0] = tok; tokW[s0] = topw[tok * 2];
    tokIdx[s1] = tok; tokW[s1] = topw[tok * 2 + 1];
    slotOf[tok * 2] = s0; slotOf[tok * 2 + 1] = s1;
    s0s = s0; s1s = s1;
  }
  __syncthreads();
  s4v v = ((const s4v*)(hH + (long long)tok * DM))[tid];
  ((s4v*)(Xg + (long long)s0s * DM))[tid] = v;
  ((s4v*)(Xg + (long long)s1s * DM))[tid] = v;
}

__global__ __launch_bounds__(256)
void moe_ln_final(const float* __restrict__ x, const float* __restrict__ eo,
                  long long pC, const int* __restrict__ slotOf,
                  const int* __restrict__ topi, const float* __restrict__ topw,
                  const float* __restrict__ b2, const float* __restrict__ g,
                  const float* __restrict__ b, ushort_t* __restrict__ outH)
{
  int tok = blockIdx.x, tid = threadIdx.x;
  int s0 = slotOf[tok * 2], s1 = slotOf[tok * 2 + 1];
  int e0 = topi[tok * 2], e1 = topi[tok * 2 + 1];
  float w0 = topw[tok * 2], w1 = topw[tok * 2 + 1];
  float4 a  = ((const float4*)(eo + (long long)s0 * DM))[tid];
  float4 a2 = ((const float4*)(eo + pC + (long long)s0 * DM))[tid];
  float4 bb1= ((const float4*)(eo + (long long)s1 * DM))[tid];
  float4 bb2= ((const float4*)(eo + pC + (long long)s1 * DM))[tid];
  float4 ba = ((const float4*)(b2 + (long long)e0 * DM))[tid];
  float4 bbb= ((const float4*)(b2 + (long long)e1 * DM))[tid];
  float4 v = ((const float4*)(x + (long long)tok * DM))[tid];
  v.x += w0 * (a.x + a2.x + ba.x) + w1 * (bb1.x + bb2.x + bbb.x);
  v.y += w0 * (a.y + a2.y + ba.y) + w1 * (bb1.y + bb2.y + bbb.y);
  v.z += w0 * (a.z + a2.z + ba.z) + w1 * (bb1.z + bb2.z + bbb.z);
  v.w += w0 * (a.w + a2.w + ba.w) + w1 * (bb1.w + bb2.w + bbb.w);
  __shared__ float sm1[4], sm2[4];
  float s = v.x + v.y + v.z + v.w;
  for (int o = 32; o > 0; o >>= 1) s += __shfl_down(s, o);
  if ((tid & 63) == 0) sm1[tid >> 6] = s;
  __syncthreads();
  float mean = (sm1[0] + sm1[1] + sm1[2] + sm1[3]) * (1.0f / DM);
  float d0 = v.x - mean, d1 = v.y - mean, d2 = v.z - mean, d3 = v.w - mean;
  float q = d0 * d0 + d1 * d1 + d2 * d2 + d3 * d3;
  for (int o = 32; o > 0; o >>= 1) q += __shfl_down(q, o);
  if ((tid & 63) == 0) sm2[tid >> 6] = q;
  __syncthreads();
  float var = (sm2[0] + sm2[1] + sm2[2] + sm2[3]) * (1.0f / DM);
  float rstd = rsqrtf(var + 1e-5f);
  float4 gv = ((const float4*)g)[tid];
  float4 bv = ((const float4*)b)[tid];
  long long base = (long long)tok * DM + tid * 4;
  outH[base + 0] = f2b(d0 * rstd * gv.x + bv.x);
  outH[base + 1] = f2b(d1 * rstd * gv.y + bv.y);
  outH[base + 2] = f2b(d2 * rstd * gv.z + bv.z);
  outH[base + 3] = f2b(d3 * rstd * gv.w + bv.w);
}

extern "C" void kernel_launch(void* const* d_in, const int* in_sizes, int n_in,
                              void* d_out, int out_size, void* d_ws, size_t ws_size,
                              hipStream_t stream)
{
  const int* ids = (const int*)d_in[0];
  const float* embed_w = (const float*)d_in[1];
  const float* pos_w   = (const float*)d_in[2];
  const float* ln1_g[2] = {(const float*)d_in[3],  (const float*)d_in[11]};
  const float* ln1_b[2] = {(const float*)d_in[4],  (const float*)d_in[12]};
  const float* in_w[2]  = {(const float*)d_in[5],  (const float*)d_in[13]};
  const float* in_b[2]  = {(const float*)d_in[6],  (const float*)d_in[14]};
  const float* out_w[2] = {(const float*)d_in[7],  (const float*)d_in[15]};
  const float* out_b[2] = {(const float*)d_in[8],  (const float*)d_in[16]};
  const float* ln2_g[2] = {(const float*)d_in[9],  (const float*)d_in[17]};
  const float* ln2_b[2] = {(const float*)d_in[10], (const float*)d_in[18]};
  const float* ffn_w1 = (const float*)d_in[19];
  const float* ffn_b1 = (const float*)d_in[20];
  const float* ffn_w2 = (const float*)d_in[21];
  const float* ffn_b2 = (const float*)d_in[22];
  const float* gate_w = (const float*)d_in[23];
  const float* gate_b = (const float*)d_in[24];
  const float* moe_w1 = (const float*)d_in[25];
  const float* moe_b1 = (const float*)d_in[26];
  const float* moe_w2 = (const float*)d_in[27];
  const float* moe_b2 = (const float*)d_in[28];
  const float* norm_g = (const float*)d_in[29];
  const float* norm_b = (const float*)d_in[30];
  const float* head_w = (const float*)d_in[31];

  char* ob = (char*)d_out;
  size_t off = 0;
  auto alloc = [&](size_t bytes) {
    char* p = ob + off;
    off = (off + bytes + 255) & ~(size_t)255;
    return p;
  };
  float*    x      = (float*)alloc((size_t)SQ * DM * 4);
  ushort_t* hbufH  = (ushort_t*)alloc((size_t)SQ * DM * 2);
  ushort_t* hbufL  = (ushort_t*)alloc((size_t)SQ * DM * 2);
  ushort_t* qkvH   = (ushort_t*)alloc((size_t)SQ * 3 * DM * 2);   // ┐
  ushort_t* qkvL   = (ushort_t*)alloc((size_t)SQ * 3 * DM * 2);   // │ w2b
  ushort_t* VtH    = (ushort_t*)alloc((size_t)NH * HDIM * SQ * 2);// │ 64MiB
  ushort_t* VtL    = (ushort_t*)alloc((size_t)NH * HDIM * SQ * 2);// │
  char*     resv   = (char*)alloc((size_t)32 << 20);              // ┘ filler
  ushort_t* attnH  = (ushort_t*)alloc((size_t)SQ * DM * 2);
  ushort_t* attnL  = (ushort_t*)alloc((size_t)SQ * DM * 2);
  ushort_t* Xg     = (ushort_t*)alloc((size_t)2 * SQ * DM * 2);
  int*      topi   = (int*)alloc(SQ * 2 * 4);
  float*    topw   = (float*)alloc(SQ * 2 * 4);
  int*      tokIdx = (int*)alloc(2 * SQ * 4);
  float*    tokW   = (float*)alloc(2 * SQ * 4);
  int*      slotOf = (int*)alloc(2 * SQ * 4);
  int*      counts = (int*)alloc(256);
  int*      offsb  = (int*)alloc(256);
  int*      cursors= (int*)alloc(256);
  ushort_t* ffnH   = (ushort_t*)alloc((size_t)SQ * FFD * 2);      // ┐ moehid
  ushort_t* ffnL   = (ushort_t*)alloc((size_t)SQ * FFD * 2);      // ┘ 32MiB
  float*    eo     = (float*)alloc((size_t)2 * 2 * SQ * DM * 4);  // 32MiB (also KS partials)
  ushort_t* inwH[2], *inwL[2], *outwH[2], *outwL[2];
  ushort_t* wsplit0 = (ushort_t*)alloc(0);
  inwH[0]  = (ushort_t*)alloc((size_t)3 * DM * DM * 2);
  inwL[0]  = (ushort_t*)alloc((size_t)3 * DM * DM * 2);
  inwH[1]  = (ushort_t*)alloc((size_t)3 * DM * DM * 2);
  inwL[1]  = (ushort_t*)alloc((size_t)3 * DM * DM * 2);
  outwH[0] = (ushort_t*)alloc((size_t)DM * DM * 2);
  outwL[0] = (ushort_t*)alloc((size_t)DM * DM * 2);
  outwH[1] = (ushort_t*)alloc((size_t)DM * DM * 2);
  outwL[1] = (ushort_t*)alloc((size_t)DM * DM * 2);
  ushort_t* f1H = (ushort_t*)alloc((size_t)FFD * DM * 2);
  ushort_t* f1L = (ushort_t*)alloc((size_t)FFD * DM * 2);
  ushort_t* f2H = (ushort_t*)alloc((size_t)DM * FFD * 2);
  ushort_t* f2L = (ushort_t*)alloc((size_t)DM * FFD * 2);
  ushort_t* moe_w1b = wsplit0;            // 64 MiB over weight planes
  ushort_t* moe_w2b = qkvH;               // 64 MiB over qkv+Vt+resv
  ushort_t* moehid  = ffnH;               // 32 MiB over ffn planes
  float*    pp      = eo;                 // KS partial planes
  const long long eoPC = (long long)2 * SQ * DM;
  const long long ppPC = (long long)SQ * DM;
  ushort_t* hfin    = (ushort_t*)d_ws;
  bool wsBig = ws_size >= ((size_t)70 << 20);
  ushort_t* head_wb = (ushort_t*)((char*)d_ws + ((size_t)4 << 20));
  (void)resv;

  embed_kernel<<<SQ, 256, 0, stream>>>(ids, embed_w, pos_w, x, counts);
  cvt_split2<<<dim3(512, 2), 256, 0, stream>>>(
      in_w[0], inwH[0], inwL[0], in_w[1], inwH[1], inwL[1], 3 * DM * DM / 4);
  cvt_split2<<<dim3(512, 2), 256, 0, stream>>>(
      out_w[0], outwH[0], outwL[0], out_w[1], outwH[1], outwL[1], DM * DM / 4);
  cvt_split2<<<dim3(512, 2), 256, 0, stream>>>(
      ffn_w1, f1H, f1L, ffn_w2, f2H, f2L, FFD * DM / 4);
  if (wsBig)
    cvt_bf16<<<1024, 256, 0, stream>>>(head_w, head_wb, NVOC * DM / 4);

  // ---- Layer 0 ----
  ln_fused<0, 0><<<SQ, 256, 0, stream>>>(x, nullptr, 0, nullptr,
                                         ln1_g[0], ln1_b[0], hbufH, hbufL);
  k_qkv<<<dim3(16, 24, 1), 256, 0, stream>>>(
      hbufH, hbufL, DM, 0, inwH[0], inwL[0], DM, 0,
      nullptr, qkvH, qkvL, 3 * DM, 0, 0,
      SQ, 3 * DM, DM, in_b[0], 1.f, VtH, VtL);
  k_attn<<<dim3(SQ / 64, NH), 256, 0, stream>>>(qkvH, qkvL, VtH, VtL,
                                                attnH, attnL);
  k_outp<<<dim3(16, 16, 4), 256, 0, stream>>>(
      attnH, attnL, DM, 0, outwH[0], outwL[0], DM, 0,
      pp, nullptr, nullptr, DM, 0, ppPC,
      SQ, DM, DM / 4, nullptr, 1.f, nullptr, nullptr);
  ln_fused<0, 4><<<SQ, 256, 0, stream>>>(x, pp, ppPC, out_b[0],
                                         ln2_g[0], ln2_b[0], hbufH, hbufL);
  k_ffn1<<<dim3(16, 32, 1), 256, 0, stream>>>(
      hbufH, hbufL, DM, 0, f1H, f1L, DM, 0,
      nullptr, ffnH, ffnL, FFD, 0, 0,
      SQ, FFD, DM, ffn_b1, 1.f, nullptr, nullptr);
  k_ffn2<<<dim3(16, 16, 2), 256, 0, stream>>>(
      ffnH, ffnL, FFD, 0, f2H, f2L, FFD, 0,
      pp, nullptr, nullptr, DM, 0, ppPC,
      SQ, DM, FFD / 2, nullptr, 1.f, nullptr, nullptr);
  // ---- Layer 1 ----
  ln_fused<0, 2><<<SQ, 256, 0, stream>>>(x, pp, ppPC, ffn_b2,
                                         ln1_g[1], ln1_b[1], hbufH, hbufL);
  k_qkv<<<dim3(16, 24, 1), 256, 0, stream>>>(
      hbufH, hbufL, DM, 0, inwH[1], inwL[1], DM, 0,
      nullptr, qkvH, qkvL, 3 * DM, 0, 0,
      SQ, 3 * DM, DM, in_b[1], 1.f, VtH, VtL);
  k_attn<<<dim3(SQ / 64, NH), 256, 0, stream>>>(qkvH, qkvL, VtH, VtL,
                                                attnH, attnL);
  k_outp<<<dim3(16, 16, 4), 256, 0, stream>>>(
      attnH, attnL, DM, 0, outwH[1], outwL[1], DM, 0,
      pp, nullptr, nullptr, DM, 0, ppPC,
      SQ, DM, DM / 4, nullptr, 1.f, nullptr, nullptr);
  cvt_bf16_2<<<dim3(2048, 2), 256, 0, stream>>>(
      moe_w1, moe_w1b, moe_w2, moe_w2b, 8 * FFD * DM / 4);
  ln_gate_top2<<<SQ, 256, 0, stream>>>(x, pp, ppPC, out_b[1],
                                       ln2_g[1], ln2_b[1], gate_w, gate_b,
                                       topi, topw, counts, hbufH);
  moe_prefix<<<1, 64, 0, stream>>>(counts, offsb, cursors);
  moe_gather<<<SQ, 256, 0, stream>>>(hbufH, topi, topw, offsb, cursors,
                                     tokIdx, tokW, slotOf, Xg);
  k_moe1<<<dim3(32, 16, 8), 256, 0, stream>>>(
      Xg, DM, 0, moe_w1b, DM, (long long)FFD * DM,
      moehid, FFD, 0, 0, SQ, FFD, DM, moe_b1, FFD, offsb);
  k_moe2<<<dim3(8, 16, 16), 256, 0, stream>>>(
      moehid, FFD, 0, moe_w2b, FFD, (long long)DM * FFD,
      eo, DM, 0, eoPC, SQ, DM, FFD, nullptr, 0, offsb);
  moe_ln_final<<<SQ, 256, 0, stream>>>(x, eo, eoPC, slotOf, topi, topw,
                                       moe_b2, norm_g, norm_b, hfin);
  if (wsBig)
    k_head_bf<<<dim3(8, 250, 1), 256, 0, stream>>>(
        hfin, DM, 0, head_wb, DM, 0, d_out, NVOC, 0, 0,
        SQ, NVOC, DM, nullptr, 0, nullptr);
  else
    k_head_f<<<dim3(8, 250, 1), 256, 0, stream>>>(
        hfin, DM, 0, head_w, DM, 0, d_out, NVOC, 0, 0,
        SQ, NVOC, DM, nullptr, 0, nullptr);
}

// Round 22
// 1112.444 us; speedup vs baseline: 1.0169x; 1.0119x over previous
//
#include <hip/hip_runtime.h>
#include <hip/hip_bf16.h>
#include <math.h>

typedef unsigned short ushort_t;
typedef __attribute__((ext_vector_type(8))) __bf16 bf16x8;
typedef __attribute__((ext_vector_type(4))) float f32x4;
typedef __attribute__((ext_vector_type(8))) short s8v;
typedef __attribute__((ext_vector_type(4))) short s4v;

#define SQ 2048
#define DM 1024
#define NH 16
#define HDIM 64
#define FFD 4096
#define NVOC 32000

__device__ inline float b2f(unsigned short u) {
  union { unsigned int i; float f; } x; x.i = ((unsigned int)u) << 16; return x.f;
}
__device__ inline unsigned short f2b(float f) {
  __hip_bfloat16 h = __float2bfloat16(f);
  return *reinterpret_cast<unsigned short*>(&h);
}
__device__ inline void split2(float x, ushort_t& h, ushort_t& l) {
  h = f2b(x);
  l = f2b(x - b2f(h));
}
__device__ inline float geluf(float v) {
  return 0.5f * v * (1.0f + erff(v * 0.70710678118654752f));
}
__device__ __forceinline__ void gld16(const void* g, void* l) {
  __builtin_amdgcn_global_load_lds(
      (const __attribute__((address_space(1))) void*)g,
      (__attribute__((address_space(3))) void*)l, 16, 0, 0);
}
#define MFMA __builtin_amdgcn_mfma_f32_16x16x32_bf16

// ---------------------------------------------------------------------------
// Split GEMM engine (pre-gate math), 2-phase double-buffered.
// EPI: 2 f32 partial store (kc*pC), 4 gelu+bias split-store,
//      5 split-store+bias with V-region (n0>=2048) written TRANSPOSED to TH/TL.
// ---------------------------------------------------------------------------
template<int EPI, int NT, int KS>
__device__ __forceinline__ void gemmsp_body(
    const ushort_t* __restrict__ AH, const ushort_t* __restrict__ AL,
    int lda, long long bA,
    const ushort_t* __restrict__ BH, const ushort_t* __restrict__ BL,
    int ldb, long long bB,
    float* __restrict__ C, ushort_t* __restrict__ CH, ushort_t* __restrict__ CL,
    int ldc, long long bC, long long pC,
    int M, int N, int K, const float* __restrict__ bias, float alpha,
    ushort_t* __restrict__ TH, ushort_t* __restrict__ TL)
{
  int z = blockIdx.z, h = z / KS, kc = z % KS;
  const ushort_t* AHp = AH + (long long)h * bA + (long long)kc * K;
  const ushort_t* ALp = AL + (long long)h * bA + (long long)kc * K;
  const ushort_t* BHp = BH + (long long)h * bB + (long long)kc * K;
  const ushort_t* BLp = BL + (long long)h * bB + (long long)kc * K;
  int m0 = blockIdx.x * 128, n0 = blockIdx.y * NT;
  const int NF = NT / 32;

  __shared__ __align__(16) ushort_t sAH[2][128 * 32], sAL[2][128 * 32];
  __shared__ __align__(16) ushort_t sBH[2][NT * 32],  sBL[2][NT * 32];

  int tid = threadIdx.x, lane = tid & 63, wave = tid >> 6;
  int wr = (wave >> 1) * 64, wc = (wave & 1) * (NT >> 1);
  int l15 = lane & 15, l4 = lane >> 4;

  f32x4 acc[4][NF];
#pragma unroll
  for (int m = 0; m < 4; ++m)
#pragma unroll
    for (int n = 0; n < NF; ++n) acc[m][n] = (f32x4){0.f, 0.f, 0.f, 0.f};

  auto stageG = [&](int buf, int k0) {
#pragma unroll
    for (int i = 0; i < 2; ++i) {
      int fi = i * 2048 + tid * 8;
      int r = fi >> 5, chk = (fi >> 3) & 3;
      int scol = ((chk ^ ((r >> 1) & 3)) << 3);
      int ra = m0 + r; if (ra > M - 1) ra = M - 1;
      long long go = (long long)ra * lda + k0 + scol;
      gld16(AHp + go, &sAH[buf][fi]);
      gld16(ALp + go, &sAL[buf][fi]);
    }
#pragma unroll
    for (int i = 0; i < NT / 64; ++i) {
      int fi = i * 2048 + tid * 8;
      int r = fi >> 5, chk = (fi >> 3) & 3;
      int scol = ((chk ^ ((r >> 1) & 3)) << 3);
      int rb = n0 + r; if (rb > N - 1) rb = N - 1;
      long long go = (long long)rb * ldb + k0 + scol;
      gld16(BHp + go, &sBH[buf][fi]);
      gld16(BLp + go, &sBL[buf][fi]);
    }
  };

  int nIt = K >> 5;
  stageG(0, 0);
  for (int it = 0; it < nIt; ++it) {
    int cur = it & 1;
    __syncthreads();
    if (it + 1 < nIt) stageG(cur ^ 1, (it + 1) << 5);
    bf16x8 ah[4], al[4], bh[NF], bl[NF];
#pragma unroll
    for (int m = 0; m < 4; ++m) {
      int r = wr + m * 16 + l15;
      int o = r * 32 + ((l4 ^ ((r >> 1) & 3)) << 3);
      ah[m] = *(const bf16x8*)&sAH[cur][o];
      al[m] = *(const bf16x8*)&sAL[cur][o];
    }
#pragma unroll
    for (int n = 0; n < NF; ++n) {
      int r = wc + n * 16 + l15;
      int o = r * 32 + ((l4 ^ ((r >> 1) & 3)) << 3);
      bh[n] = *(const bf16x8*)&sBH[cur][o];
      bl[n] = *(const bf16x8*)&sBL[cur][o];
    }
#pragma unroll
    for (int m = 0; m < 4; ++m)
#pragma unroll
      for (int n = 0; n < NF; ++n) {
        acc[m][n] = MFMA(ah[m], bh[n], acc[m][n], 0, 0, 0);
        acc[m][n] = MFMA(al[m], bh[n], acc[m][n], 0, 0, 0);
        acc[m][n] = MFMA(ah[m], bl[n], acc[m][n], 0, 0, 0);
      }
  }

  if (EPI == 5 && n0 >= 2 * DM) {
#pragma unroll
    for (int m = 0; m < 4; ++m) {
      int rbase = m0 + wr + m * 16 + l4 * 4;
#pragma unroll
      for (int n = 0; n < NF; ++n) {
        int c = n0 + wc + n * 16 + l15;
        int d = c - 2 * DM;
        float bv = bias[c];
        s4v hv, lv;
#pragma unroll
        for (int q = 0; q < 4; ++q) {
          ushort_t hh, ll; split2(acc[m][n][q] + bv, hh, ll);
          hv[q] = (short)hh; lv[q] = (short)ll;
        }
        *(s4v*)&TH[(long long)d * SQ + rbase] = hv;
        *(s4v*)&TL[(long long)d * SQ + rbase] = lv;
      }
    }
    return;
  }

#pragma unroll
  for (int m = 0; m < 4; ++m) {
#pragma unroll
    for (int n = 0; n < NF; ++n) {
      int c = n0 + wc + n * 16 + l15;
      if (c >= N) continue;
      float bv = (EPI == 4 || EPI == 5) ? bias[c] : 0.f;
#pragma unroll
      for (int q = 0; q < 4; ++q) {
        int rr = m0 + wr + m * 16 + l4 * 4 + q;
        if (rr >= M) continue;
        float v = acc[m][n][q];
        if (EPI == 5) {
          ushort_t hh, ll; split2(v + bv, hh, ll);
          long long o = (long long)rr * ldc + c; CH[o] = hh; CL[o] = ll;
        } else if (EPI == 2) {
          C[(long long)kc * pC + (long long)rr * ldc + (long long)h * bC + c] = v;
        } else if (EPI == 4) {
          ushort_t hh, ll; split2(geluf(v + bv), hh, ll);
          long long o = (long long)rr * ldc + c; CH[o] = hh; CL[o] = ll;
        }
      }
    }
  }
}

#define SP_ARGS const ushort_t* AH, const ushort_t* AL, int lda, long long bA, \
    const ushort_t* BH, const ushort_t* BL, int ldb, long long bB, \
    float* C, ushort_t* CH, ushort_t* CL, int ldc, long long bC, long long pC, \
    int M, int N, int K, const float* bias, float alpha, \
    ushort_t* TH, ushort_t* TL
#define SP_PASS AH, AL, lda, bA, BH, BL, ldb, bB, C, CH, CL, ldc, bC, pC, M, N, K, bias, alpha, TH, TL

__global__ __launch_bounds__(256) void k_qkv (SP_ARGS) { gemmsp_body<5,128,1>(SP_PASS); }
__global__ __launch_bounds__(256) void k_outp(SP_ARGS) { gemmsp_body<2, 64,4>(SP_PASS); }
__global__ __launch_bounds__(256) void k_ffn1(SP_ARGS) { gemmsp_body<4,128,1>(SP_PASS); }
__global__ __launch_bounds__(256) void k_ffn2(SP_ARGS) { gemmsp_body<2, 64,2>(SP_PASS); }

// ---------------------------------------------------------------------------
// Fused flash attention, split-f32 precision. Grid (32,16). K/V dbuf.
// T5: s_setprio(1) around QK^T and PV MFMA clusters — 2 independent
// blocks/CU at different phases give the CU scheduler something to
// arbitrate (m191 regime: attn +4-7%; GEMM lockstep case is null).
// ---------------------------------------------------------------------------
__global__ __launch_bounds__(256)
void k_attn(const ushort_t* __restrict__ qkvH, const ushort_t* __restrict__ qkvL,
            const ushort_t* __restrict__ VtH, const ushort_t* __restrict__ VtL,
            ushort_t* __restrict__ aH, ushort_t* __restrict__ aL)
{
  int f = blockIdx.x + blockIdx.y * gridDim.x;
  int logical = (f & 7) * 64 + (f >> 3);
  int q0 = (logical & 31) * 64;
  int h  = logical >> 5;

  __shared__ __align__(16) ushort_t sKH[2][4096], sKL[2][4096];
  __shared__ __align__(16) ushort_t sVH[2][4096], sVL[2][4096];
  __shared__ __align__(16) ushort_t sPH[4096], sPL[4096];

  int tid = threadIdx.x, lane = tid & 63, wave = tid >> 6;
  int l15 = lane & 15, l4 = lane >> 4;

  bf16x8 qh[2], ql[2];
  {
    long long base = (long long)(q0 + wave * 16 + l15) * (3 * DM) + h * 64 + l4 * 8;
    qh[0] = *(const bf16x8*)(qkvH + base);
    qh[1] = *(const bf16x8*)(qkvH + base + 32);
    ql[0] = *(const bf16x8*)(qkvL + base);
    ql[1] = *(const bf16x8*)(qkvL + base + 32);
  }

  auto stageKV = [&](int buf, int kt) {
#pragma unroll
    for (int i = 0; i < 2; ++i) {
      int idx = i * 2048 + tid * 8;
      int row = idx >> 6, chk = (idx >> 3) & 7;
      int scol = ((chk ^ (row & 7)) << 3);
      long long gk = (long long)(kt * 64 + row) * (3 * DM) + DM + h * 64 + scol;
      long long gv = (long long)(h * 64 + row) * SQ + kt * 64 + scol;
      gld16(qkvH + gk, &sKH[buf][idx]);
      gld16(qkvL + gk, &sKL[buf][idx]);
      gld16(VtH + gv, &sVH[buf][idx]);
      gld16(VtL + gv, &sVL[buf][idx]);
    }
  };

  float mrow[4], lrow[4];
  f32x4 Oacc[4];
#pragma unroll
  for (int r = 0; r < 4; ++r) { mrow[r] = -1e30f; lrow[r] = 0.f; }
#pragma unroll
  for (int n = 0; n < 4; ++n) Oacc[n] = (f32x4){0.f, 0.f, 0.f, 0.f};

  const int NT = SQ / 64;
  stageKV(0, 0);
  for (int kt = 0; kt < NT; ++kt) {
    int cur = kt & 1;
    __syncthreads();
    if (kt + 1 < NT) stageKV(cur ^ 1, kt + 1);

    f32x4 S[4];
#pragma unroll
    for (int n = 0; n < 4; ++n) S[n] = (f32x4){0.f, 0.f, 0.f, 0.f};
    __builtin_amdgcn_s_setprio(1);
#pragma unroll
    for (int kk = 0; kk < 64; kk += 32) {
      int kkI = kk >> 5;
      bf16x8 qhf = qh[kkI], qlf = ql[kkI];
#pragma unroll
      for (int n = 0; n < 4; ++n) {
        int br = n * 16 + l15;
        int bo = br * 64 + ((((kk >> 3) + l4) ^ (br & 7)) << 3);
        bf16x8 kh = *(const bf16x8*)&sKH[cur][bo];
        bf16x8 kl = *(const bf16x8*)&sKL[cur][bo];
        S[n] = MFMA(qhf, kh, S[n], 0, 0, 0);
        S[n] = MFMA(qlf, kh, S[n], 0, 0, 0);
        S[n] = MFMA(qhf, kl, S[n], 0, 0, 0);
      }
    }
    __builtin_amdgcn_s_setprio(0);
    float tm[4], ts[4];
#pragma unroll
    for (int r = 0; r < 4; ++r) {
#pragma unroll
      for (int n = 0; n < 4; ++n) S[n][r] *= 0.125f;
      tm[r] = fmaxf(fmaxf(S[0][r], S[1][r]), fmaxf(S[2][r], S[3][r]));
    }
#pragma unroll
    for (int mk = 1; mk <= 8; mk <<= 1)
#pragma unroll
      for (int r = 0; r < 4; ++r) tm[r] = fmaxf(tm[r], __shfl_xor(tm[r], mk));
#pragma unroll
    for (int r = 0; r < 4; ++r) {
      float mn = fmaxf(mrow[r], tm[r]);
      float corr = __expf(mrow[r] - mn);
      mrow[r] = mn;
      float s = 0.f;
#pragma unroll
      for (int n = 0; n < 4; ++n) { S[n][r] = __expf(S[n][r] - mn); s += S[n][r]; }
      ts[r] = s;
      lrow[r] *= corr;
#pragma unroll
      for (int n = 0; n < 4; ++n) Oacc[n][r] *= corr;
    }
#pragma unroll
    for (int mk = 1; mk <= 8; mk <<= 1)
#pragma unroll
      for (int r = 0; r < 4; ++r) ts[r] += __shfl_xor(ts[r], mk);
#pragma unroll
    for (int r = 0; r < 4; ++r) lrow[r] += ts[r];

    {
      ushort_t* pH = &sPH[wave * 1024];
      ushort_t* pL = &sPL[wave * 1024];
#pragma unroll
      for (int n = 0; n < 4; ++n)
#pragma unroll
        for (int r = 0; r < 4; ++r) {
          int row = l4 * 4 + r, col = n * 16 + l15;
          int ad = row * 64 + (((col >> 3) ^ (row & 7)) << 3) + (col & 7);
          ushort_t hh, ll; split2(S[n][r], hh, ll);
          pH[ad] = hh; pL[ad] = ll;
        }
    }
    __syncthreads();
    __builtin_amdgcn_s_setprio(1);
#pragma unroll
    for (int kk = 0; kk < 64; kk += 32) {
      int ao = wave * 1024 + l15 * 64 + ((((kk >> 3) + l4) ^ (l15 & 7)) << 3);
      bf16x8 ph = *(const bf16x8*)&sPH[ao];
      bf16x8 pl = *(const bf16x8*)&sPL[ao];
#pragma unroll
      for (int n = 0; n < 4; ++n) {
        int br = n * 16 + l15;
        int bo = br * 64 + ((((kk >> 3) + l4) ^ (br & 7)) << 3);
        bf16x8 vh = *(const bf16x8*)&sVH[cur][bo];
        bf16x8 vl = *(const bf16x8*)&sVL[cur][bo];
        Oacc[n] = MFMA(ph, vh, Oacc[n], 0, 0, 0);
        Oacc[n] = MFMA(pl, vh, Oacc[n], 0, 0, 0);
        Oacc[n] = MFMA(ph, vl, Oacc[n], 0, 0, 0);
      }
    }
    __builtin_amdgcn_s_setprio(0);
  }

#pragma unroll
  for (int n = 0; n < 4; ++n)
#pragma unroll
    for (int r = 0; r < 4; ++r) {
      int q = q0 + wave * 16 + l4 * 4 + r;
      int d = h * 64 + n * 16 + l15;
      float val = Oacc[n][r] / lrow[r];
      ushort_t hh, ll; split2(val, hh, ll);
      long long o = (long long)q * DM + d;
      aH[o] = hh; aL[o] = ll;
    }
}

// ---------------------------------------------------------------------------
// bf16 GEMM engine "s" (MoE): BM=128, BK=32, 32KB LDS -> 5 blocks/CU (r15).
// EPI: 2 gelu(+bias) bf16 store, 7 f32 partial store via LDS-transpose.
// ---------------------------------------------------------------------------
template<int EPI, int SWAP, int KS>
__device__ __forceinline__ void gemm16s_body(
    const ushort_t* __restrict__ A, int lda, long long bA,
    const ushort_t* __restrict__ Bp0, int ldb, long long bB,
    void* __restrict__ Cv, int ldc, long long bC, long long pC,
    int M, int N, int K, const float* __restrict__ bias, int bBias,
    const int* __restrict__ offs)
{
  int bz = blockIdx.z;
  int z = bz / KS, kc = bz % KS;
  int Kc = K / KS;
  const ushort_t* Ap = A + (long long)z * bA + (long long)kc * Kc;
  const ushort_t* Bp = Bp0 + (long long)z * bB + (long long)kc * Kc;
  int rowStart = 0, Meff = M;
  if (offs) { rowStart = offs[z]; Meff = offs[z + 1] - rowStart; }
  int m0 = (SWAP ? blockIdx.y : blockIdx.x) * 128;
  if (m0 >= Meff) return;
  int n0 = (SWAP ? blockIdx.x : blockIdx.y) * 128;

  __shared__ __align__(16) char smem[32768];

  int tid = threadIdx.x, lane = tid & 63, wave = tid >> 6;
  int wr = (wave >> 1) * 64, wc = (wave & 1) * 64;
  int l15 = lane & 15, l4 = lane >> 4;

  f32x4 acc[4][4];
#pragma unroll
  for (int m = 0; m < 4; ++m)
#pragma unroll
    for (int n = 0; n < 4; ++n) acc[m][n] = (f32x4){0.f, 0.f, 0.f, 0.f};

  auto stageG = [&](int buf, int k0) {
    ushort_t* dA = (ushort_t*)(smem + buf * 8192);
    ushort_t* dB = (ushort_t*)(smem + 16384 + buf * 8192);
#pragma unroll
    for (int i = 0; i < 2; ++i) {
      int idx = i * 2048 + tid * 8;
      int row = idx >> 5, chk = (idx >> 3) & 3;
      int scol = ((chk ^ ((row >> 1) & 3)) << 3);
      int ra = m0 + row; if (ra > Meff - 1) ra = Meff - 1;
      gld16(Ap + (long long)(rowStart + ra) * lda + k0 + scol, &dA[idx]);
    }
#pragma unroll
    for (int i = 0; i < 2; ++i) {
      int idx = i * 2048 + tid * 8;
      int row = idx >> 5, chk = (idx >> 3) & 3;
      int scol = ((chk ^ ((row >> 1) & 3)) << 3);
      int rb = n0 + row; if (rb > N - 1) rb = N - 1;
      gld16(Bp + (long long)rb * ldb + k0 + scol, &dB[idx]);
    }
  };

  int nIt = Kc >> 5;
  stageG(0, 0);
  for (int it = 0; it < nIt; ++it) {
    int cur = it & 1;
    __syncthreads();
    if (it + 1 < nIt) stageG(cur ^ 1, (it + 1) << 5);
    ushort_t* As = (ushort_t*)(smem + cur * 8192);
    ushort_t* Bs = (ushort_t*)(smem + 16384 + cur * 8192);
    bf16x8 af[4], bfr[4];
#pragma unroll
    for (int m = 0; m < 4; ++m) {
      int r = wr + m * 16 + l15;
      af[m] = *(const bf16x8*)&As[r * 32 + ((l4 ^ ((r >> 1) & 3)) << 3)];
    }
#pragma unroll
    for (int n = 0; n < 4; ++n) {
      int r = wc + n * 16 + l15;
      bfr[n] = *(const bf16x8*)&Bs[r * 32 + ((l4 ^ ((r >> 1) & 3)) << 3)];
    }
#pragma unroll
    for (int m = 0; m < 4; ++m)
#pragma unroll
      for (int n = 0; n < 4; ++n)
        acc[m][n] = MFMA(af[m], bfr[n], acc[m][n], 0, 0, 0);
  }
  __syncthreads();

  if (EPI == 7) {
    float* fE = (float*)smem;
#pragma unroll
    for (int h2 = 0; h2 < 2; ++h2) {
      if ((wave >> 1) == h2) {
#pragma unroll
        for (int m = 0; m < 4; ++m)
#pragma unroll
          for (int n = 0; n < 4; ++n)
#pragma unroll
            for (int q = 0; q < 4; ++q)
              fE[(m * 16 + l4 * 4 + q) * 128 + wc + n * 16 + l15] = acc[m][n][q];
      }
      __syncthreads();
#pragma unroll
      for (int i = 0; i < 8; ++i) {
        int lin = tid + i * 256;
        int row = lin >> 5, c4 = (lin & 31) << 2;
        int gr = m0 + h2 * 64 + row;
        if (gr < Meff) {
          f32x4 v4 = *(const f32x4*)&fE[row * 128 + c4];
          long long crow = rowStart + gr;
          float* dst = (float*)Cv + (long long)kc * pC + crow * ldc + n0 + c4;
          *(f32x4*)dst = v4;
        }
      }
      __syncthreads();
    }
    return;
  }

#pragma unroll
  for (int m = 0; m < 4; ++m) {
#pragma unroll
    for (int n = 0; n < 4; ++n) {
      int c = n0 + wc + n * 16 + l15;
      if (c >= N) continue;
      float bv = (EPI == 2) ? bias[(long long)z * bBias + c] : 0.f;
#pragma unroll
      for (int q = 0; q < 4; ++q) {
        int rr = m0 + wr + m * 16 + l4 * 4 + q;
        if (rr >= Meff) continue;
        float v = acc[m][n][q];
        long long crow = rowStart + rr;
        if (EPI == 2)
          ((ushort_t*)Cv)[crow * ldc + (long long)z * bC + c] = f2b(geluf(v + bv));
      }
    }
  }
}

// ---------------------------------------------------------------------------
// bf16 GEMM engine "w" (head): BM=256 x BN=128, BK=32, wave tile 128x64.
// Per K-step 32 MFMA vs 12 ds_read -> MFMA-bound. LDS 48KB.
// ---------------------------------------------------------------------------
template<int BSRC>
__device__ __forceinline__ void gemm16w_body(
    const ushort_t* __restrict__ A, int lda,
    const void* __restrict__ Bv, int ldb,
    float* __restrict__ Cv, int ldc,
    int M, int N, int K)
{
  int bx = blockIdx.x, by = blockIdx.y;
  {
    int flat = bx + by * gridDim.x;
    int cpx = (gridDim.x * gridDim.y) >> 3;
    int s = (flat & 7) * cpx + (flat >> 3);
    bx = s % gridDim.x; by = s / gridDim.x;
  }
  int m0 = bx * 256;
  int n0 = by * 128;

  __shared__ __align__(16) char smem[49152];
  const ushort_t* Bp = (BSRC == 1) ? (const ushort_t*)Bv : nullptr;
  const float* Bf = (BSRC == 0) ? (const float*)Bv : nullptr;

  int tid = threadIdx.x, lane = tid & 63, wave = tid >> 6;
  int wr = (wave >> 1) * 128, wc = (wave & 1) * 64;
  int l15 = lane & 15, l4 = lane >> 4;

  f32x4 acc[8][4];
#pragma unroll
  for (int m = 0; m < 8; ++m)
#pragma unroll
    for (int n = 0; n < 4; ++n) acc[m][n] = (f32x4){0.f, 0.f, 0.f, 0.f};

  auto stageG = [&](int buf, int k0) {
    ushort_t* dA = (ushort_t*)(smem + buf * 16384);
    ushort_t* dB = (ushort_t*)(smem + 32768 + buf * 8192);
#pragma unroll
    for (int i = 0; i < 4; ++i) {
      int idx = i * 2048 + tid * 8;
      int row = idx >> 5, chk = (idx >> 3) & 3;
      int scol = ((chk ^ ((row >> 1) & 3)) << 3);
      int ra = m0 + row; if (ra > M - 1) ra = M - 1;
      gld16(A + (long long)ra * lda + k0 + scol, &dA[idx]);
    }
    if (BSRC == 1) {
#pragma unroll
      for (int i = 0; i < 2; ++i) {
        int idx = i * 2048 + tid * 8;
        int row = idx >> 5, chk = (idx >> 3) & 3;
        int scol = ((chk ^ ((row >> 1) & 3)) << 3);
        int rb = n0 + row; if (rb > N - 1) rb = N - 1;
        gld16(Bp + (long long)rb * ldb + k0 + scol, &dB[idx]);
      }
    } else {
#pragma unroll
      for (int i = 0; i < 4; ++i) {
        int g = tid + i * 256;
        int r = g >> 3, c4 = (g & 7) * 4;
        int rb = n0 + r; if (rb > N - 1) rb = N - 1;
        float4 fv = *(const float4*)(Bf + (long long)rb * ldb + k0 + c4);
        s4v o; o[0] = (short)f2b(fv.x); o[1] = (short)f2b(fv.y);
        o[2] = (short)f2b(fv.z); o[3] = (short)f2b(fv.w);
        int dst = r * 32 + ((((c4 >> 3) ^ ((r >> 1) & 3))) << 3) + (c4 & 7);
        *(s4v*)&dB[dst] = o;
      }
    }
  };

  int nIt = K >> 5;
  stageG(0, 0);
  for (int it = 0; it < nIt; ++it) {
    int cur = it & 1;
    __syncthreads();
    if (it + 1 < nIt) stageG(cur ^ 1, (it + 1) << 5);
    ushort_t* As = (ushort_t*)(smem + cur * 16384);
    ushort_t* Bs = (ushort_t*)(smem + 32768 + cur * 8192);
    bf16x8 af[8], bfr[4];
#pragma unroll
    for (int m = 0; m < 8; ++m) {
      int r = wr + m * 16 + l15;
      af[m] = *(const bf16x8*)&As[r * 32 + ((l4 ^ ((r >> 1) & 3)) << 3)];
    }
#pragma unroll
    for (int n = 0; n < 4; ++n) {
      int r = wc + n * 16 + l15;
      bfr[n] = *(const bf16x8*)&Bs[r * 32 + ((l4 ^ ((r >> 1) & 3)) << 3)];
    }
#pragma unroll
    for (int m = 0; m < 8; ++m)
#pragma unroll
      for (int n = 0; n < 4; ++n)
        acc[m][n] = MFMA(af[m], bfr[n], acc[m][n], 0, 0, 0);
  }
  __syncthreads();

  // LDS-transpose epilogue: 4 passes of 64x128 f32, non-temporal float4 stores
  float* fE = (float*)smem;
#pragma unroll
  for (int h2 = 0; h2 < 4; ++h2) {
    if ((wave >> 1) == (h2 >> 1)) {
#pragma unroll
      for (int mm = 0; mm < 4; ++mm) {
        int m = (h2 & 1) * 4 + mm;
#pragma unroll
        for (int n = 0; n < 4; ++n)
#pragma unroll
          for (int q = 0; q < 4; ++q)
            fE[(mm * 16 + l4 * 4 + q) * 128 + wc + n * 16 + l15] = acc[m][n][q];
      }
    }
    __syncthreads();
#pragma unroll
    for (int i = 0; i < 8; ++i) {
      int lin = tid + i * 256;
      int row = lin >> 5, c4 = (lin & 31) << 2;
      int gr = m0 + h2 * 64 + row;
      if (gr < M) {
        f32x4 v4 = *(const f32x4*)&fE[row * 128 + c4];
        float* dst = Cv + (long long)gr * ldc + n0 + c4;
        __builtin_nontemporal_store(v4, (f32x4*)dst);
      }
    }
    __syncthreads();
  }
}

#define G16_ARGS const ushort_t* A, int lda, long long bA, const void* Bv, \
    int ldb, long long bB, void* Cv, int ldc, long long bC, long long pC, \
    int M, int N, int K, const float* bias, int bBias, const int* offs
#define G16S_PASS(EPI,SWAP,KS) gemm16s_body<EPI,SWAP,KS>(A, lda, bA, \
    (const ushort_t*)Bv, ldb, bB, Cv, ldc, bC, pC, M, N, K, bias, bBias, offs)

__global__ __launch_bounds__(256) void k_moe1(G16_ARGS) { G16S_PASS(2,1,1); }
__global__ __launch_bounds__(256) void k_moe2(G16_ARGS) { G16S_PASS(7,1,2); }
__global__ __launch_bounds__(256) void k_head_bf(G16_ARGS) {
  gemm16w_body<1>(A, lda, Bv, ldb, (float*)Cv, ldc, M, N, K);
}
__global__ __launch_bounds__(256) void k_head_f(G16_ARGS) {
  gemm16w_body<0>(A, lda, Bv, ldb, (float*)Cv, ldc, M, N, K);
}

// ---------------------------------------------------------------------------
__global__ __launch_bounds__(256)
void cvt_split2(const float* __restrict__ s0, ushort_t* __restrict__ dh0,
                ushort_t* __restrict__ dl0,
                const float* __restrict__ s1, ushort_t* __restrict__ dh1,
                ushort_t* __restrict__ dl1, int n4)
{
  const float* s = blockIdx.y ? s1 : s0;
  ushort_t* dh = blockIdx.y ? dh1 : dh0;
  ushort_t* dl = blockIdx.y ? dl1 : dl0;
  int i = blockIdx.x * blockDim.x + threadIdx.x;
  int stride = gridDim.x * blockDim.x;
  for (; i < n4; i += stride) {
    float4 f = ((const float4*)s)[i];
    s4v h, l; ushort_t hh, ll;
    split2(f.x, hh, ll); h[0] = (short)hh; l[0] = (short)ll;
    split2(f.y, hh, ll); h[1] = (short)hh; l[1] = (short)ll;
    split2(f.z, hh, ll); h[2] = (short)hh; l[2] = (short)ll;
    split2(f.w, hh, ll); h[3] = (short)hh; l[3] = (short)ll;
    ((s4v*)dh)[i] = h; ((s4v*)dl)[i] = l;
  }
}

__global__ __launch_bounds__(256)
void cvt_bf16(const float* __restrict__ s, ushort_t* __restrict__ d, int n4)
{
  int i = blockIdx.x * blockDim.x + threadIdx.x;
  int stride = gridDim.x * blockDim.x;
  for (; i < n4; i += stride) {
    float4 f = ((const float4*)s)[i];
    s4v o; o[0] = (short)f2b(f.x); o[1] = (short)f2b(f.y);
    o[2] = (short)f2b(f.z); o[3] = (short)f2b(f.w);
    ((s4v*)d)[i] = o;
  }
}

__global__ __launch_bounds__(256)
void cvt_bf16_2(const float* __restrict__ s0, ushort_t* __restrict__ d0,
                const float* __restrict__ s1, ushort_t* __restrict__ d1, int n4)
{
  const float* s = blockIdx.y ? s1 : s0;
  ushort_t* d = blockIdx.y ? d1 : d0;
  int i = blockIdx.x * blockDim.x + threadIdx.x;
  int stride = gridDim.x * blockDim.x;
  for (; i < n4; i += stride) {
    float4 f = ((const float4*)s)[i];
    s4v o; o[0] = (short)f2b(f.x); o[1] = (short)f2b(f.y);
    o[2] = (short)f2b(f.z); o[3] = (short)f2b(f.w);
    ((s4v*)d)[i] = o;
  }
}

__global__ __launch_bounds__(256)
void embed_kernel(const int* __restrict__ ids, const float* __restrict__ ew,
                  const float* __restrict__ pw, float* __restrict__ x,
                  int* __restrict__ counts)
{
  int srow = blockIdx.x, tid = threadIdx.x;
  if (srow == 0 && tid < 8) counts[tid] = 0;
  int id = ids[srow];
  const float4 e = *(const float4*)(ew + (long long)id * DM + tid * 4);
  const float4 p = *(const float4*)(pw + (long long)srow * DM + tid * 4);
  float4* xr = (float4*)(x + (long long)srow * DM) + tid;
  *xr = make_float4(e.x + p.x, e.y + p.y, e.z + p.z, e.w + p.w);
}

template<int MODE, int NP>
__global__ __launch_bounds__(256)
void ln_fused(float* __restrict__ x, const float* __restrict__ P, long long pC,
              const float* __restrict__ bias_pre,
              const float* __restrict__ g, const float* __restrict__ b,
              ushort_t* __restrict__ outH, ushort_t* __restrict__ outL)
{
  int row = blockIdx.x, tid = threadIdx.x;
  long long xo = (long long)row * DM + tid * 4;
  float4 v = *(const float4*)(x + xo);
  if (NP > 0) {
    float4 bp = *(const float4*)(bias_pre + tid * 4);
    float sx = bp.x, sy = bp.y, sz = bp.z, sw = bp.w;
#pragma unroll
    for (int p = 0; p < NP; ++p) {
      float4 pv = *(const float4*)(P + (long long)p * pC + xo);
      sx += pv.x; sy += pv.y; sz += pv.z; sw += pv.w;
    }
    v.x += sx; v.y += sy; v.z += sz; v.w += sw;
    *(float4*)(x + xo) = v;
  }
  __shared__ float sm1[4], sm2[4];
  float s = v.x + v.y + v.z + v.w;
  for (int o = 32; o > 0; o >>= 1) s += __shfl_down(s, o);
  if ((tid & 63) == 0) sm1[tid >> 6] = s;
  __syncthreads();
  float mean = (sm1[0] + sm1[1] + sm1[2] + sm1[3]) * (1.0f / DM);
  float d0 = v.x - mean, d1 = v.y - mean, d2 = v.z - mean, d3 = v.w - mean;
  float q = d0 * d0 + d1 * d1 + d2 * d2 + d3 * d3;
  for (int o = 32; o > 0; o >>= 1) q += __shfl_down(q, o);
  if ((tid & 63) == 0) sm2[tid >> 6] = q;
  __syncthreads();
  float var = (sm2[0] + sm2[1] + sm2[2] + sm2[3]) * (1.0f / DM);
  float rstd = rsqrtf(var + 1e-5f);
  float4 gv = ((const float4*)g)[tid];
  float4 bv = ((const float4*)b)[tid];
  float o0 = d0 * rstd * gv.x + bv.x, o1 = d1 * rstd * gv.y + bv.y;
  float o2 = d2 * rstd * gv.z + bv.z, o3 = d3 * rstd * gv.w + bv.w;
  long long base = (long long)row * DM + tid * 4;
  if (MODE == 0) {
    ushort_t hh, ll;
    split2(o0, hh, ll); outH[base + 0] = hh; outL[base + 0] = ll;
    split2(o1, hh, ll); outH[base + 1] = hh; outL[base + 1] = ll;
    split2(o2, hh, ll); outH[base + 2] = hh; outL[base + 2] = ll;
    split2(o3, hh, ll); outH[base + 3] = hh; outL[base + 3] = ll;
  } else {
    outH[base + 0] = f2b(o0); outH[base + 1] = f2b(o1);
    outH[base + 2] = f2b(o2); outH[base + 3] = f2b(o3);
  }
}

__global__ __launch_bounds__(256)
void ln_gate_top2(float* __restrict__ x, const float* __restrict__ P,
                  long long pC, const float* __restrict__ bias_pre,
                  const float* __restrict__ g, const float* __restrict__ b,
                  const float* __restrict__ gw, const float* __restrict__ gb,
                  int* __restrict__ topi, float* __restrict__ topw,
                  int* __restrict__ counts, ushort_t* __restrict__ outH)
{
  int row = blockIdx.x, tid = threadIdx.x;
  long long xo = (long long)row * DM + tid * 4;
  float4 v = *(const float4*)(x + xo);
  {
    float4 bp = *(const float4*)(bias_pre + tid * 4);
    float sx = bp.x, sy = bp.y, sz = bp.z, sw = bp.w;
#pragma unroll
    for (int p = 0; p < 4; ++p) {
      float4 pv = *(const float4*)(P + (long long)p * pC + xo);
      sx += pv.x; sy += pv.y; sz += pv.z; sw += pv.w;
    }
    v.x += sx; v.y += sy; v.z += sz; v.w += sw;
    *(float4*)(x + xo) = v;
  }
  __shared__ float sm1[4], sm2[4];
  __shared__ float se[8][4];
  float s = v.x + v.y + v.z + v.w;
  for (int o = 32; o > 0; o >>= 1) s += __shfl_down(s, o);
  if ((tid & 63) == 0) sm1[tid >> 6] = s;
  __syncthreads();
  float mean = (sm1[0] + sm1[1] + sm1[2] + sm1[3]) * (1.0f / DM);
  float d0 = v.x - mean, d1 = v.y - mean, d2 = v.z - mean, d3 = v.w - mean;
  float q = d0 * d0 + d1 * d1 + d2 * d2 + d3 * d3;
  for (int o = 32; o > 0; o >>= 1) q += __shfl_down(q, o);
  if ((tid & 63) == 0) sm2[tid >> 6] = q;
  __syncthreads();
  float var = (sm2[0] + sm2[1] + sm2[2] + sm2[3]) * (1.0f / DM);
  float rstd = rsqrtf(var + 1e-5f);
  float4 gv = ((const float4*)g)[tid];
  float4 bv = ((const float4*)b)[tid];
  float h0 = d0 * rstd * gv.x + bv.x, h1 = d1 * rstd * gv.y + bv.y;
  float h2 = d2 * rstd * gv.z + bv.z, h3 = d3 * rstd * gv.w + bv.w;
  long long base = (long long)row * DM + tid * 4;
  outH[base + 0] = f2b(h0); outH[base + 1] = f2b(h1);
  outH[base + 2] = f2b(h2); outH[base + 3] = f2b(h3);
#pragma unroll
  for (int e = 0; e < 8; ++e) {
    float4 w = ((const float4*)(gw + (long long)e * DM))[tid];
    float p = h0 * w.x + h1 * w.y + h2 * w.z + h3 * w.w;
    for (int o = 32; o > 0; o >>= 1) p += __shfl_down(p, o);
    if ((tid & 63) == 0) se[e][tid >> 6] = p;
  }
  __syncthreads();
  if (tid == 0) {
    float sc[8];
#pragma unroll
    for (int e = 0; e < 8; ++e)
      sc[e] = se[e][0] + se[e][1] + se[e][2] + se[e][3] + gb[e];
    int i1 = 0; float m1 = sc[0];
    for (int e = 1; e < 8; ++e) if (sc[e] > m1) { m1 = sc[e]; i1 = e; }
    int i2 = -1; float m2 = -1e30f;
    for (int e = 0; e < 8; ++e) if (e != i1 && sc[e] > m2) { m2 = sc[e]; i2 = e; }
    float e2 = __expf(m2 - m1);
    float w1 = 1.f / (1.f + e2);
    topi[row * 2] = i1; topi[row * 2 + 1] = i2;
    topw[row * 2] = w1; topw[row * 2 + 1] = 1.f - w1;
    atomicAdd(&counts[i1], 1);
    atomicAdd(&counts[i2], 1);
  }
}

__global__ void moe_prefix(const int* __restrict__ counts, int* __restrict__ offs,
                           int* __restrict__ cursors)
{
  if (threadIdx.x == 0 && blockIdx.x == 0) {
    int a = 0;
    for (int e = 0; e < 8; ++e) { offs[e] = a; a += counts[e]; cursors[e] = 0; }
    offs[8] = a;
  }
}

__global__ __launch_bounds__(256)
void moe_gather(const ushort_t* __restrict__ hH, const int* __restrict__ topi,
                const float* __restrict__ topw, const int* __restrict__ offs,
                int* __restrict__ cursors, int* __restrict__ tokIdx,
                float* __restrict__ tokW, int* __restrict__ slotOf,
                ushort_t* __restrict__ Xg)
{
  int tok = blockIdx.x, tid = threadIdx.x;
  __shared__ int s0s, s1s;
  if (tid == 0) {
    int e0 = topi[tok * 2], e1 = topi[tok * 2 + 1];
    int s0 = offs[e0] + atomicAdd(&cursors[e0], 1);
    int s1 = offs[e1] + atomicAdd(&cursors[e1], 1);
    tokIdx[s0] = tok; tokW[s0] = topw[tok * 2];
    tokIdx[s1] = tok; tokW[s1] = topw[tok * 2 + 1];
    slotOf[tok * 2] = s0; slotOf[tok * 2 + 1] = s1;
    s0s = s0; s1s = s1;
  }
  __syncthreads();
  s4v v = ((const s4v*)(hH + (long long)tok * DM))[tid];
  ((s4v*)(Xg + (long long)s0s * DM))[tid] = v;
  ((s4v*)(Xg + (long long)s1s * DM))[tid] = v;
}

__global__ __launch_bounds__(256)
void moe_ln_final(const float* __restrict__ x, const float* __restrict__ eo,
                  long long pC, const int* __restrict__ slotOf,
                  const int* __restrict__ topi, const float* __restrict__ topw,
                  const float* __restrict__ b2, const float* __restrict__ g,
                  const float* __restrict__ b, ushort_t* __restrict__ outH)
{
  int tok = blockIdx.x, tid = threadIdx.x;
  int s0 = slotOf[tok * 2], s1 = slotOf[tok * 2 + 1];
  int e0 = topi[tok * 2], e1 = topi[tok * 2 + 1];
  float w0 = topw[tok * 2], w1 = topw[tok * 2 + 1];
  float4 a  = ((const float4*)(eo + (long long)s0 * DM))[tid];
  float4 a2 = ((const float4*)(eo + pC + (long long)s0 * DM))[tid];
  float4 bb1= ((const float4*)(eo + (long long)s1 * DM))[tid];
  float4 bb2= ((const float4*)(eo + pC + (long long)s1 * DM))[tid];
  float4 ba = ((const float4*)(b2 + (long long)e0 * DM))[tid];
  float4 bbb= ((const float4*)(b2 + (long long)e1 * DM))[tid];
  float4 v = ((const float4*)(x + (long long)tok * DM))[tid];
  v.x += w0 * (a.x + a2.x + ba.x) + w1 * (bb1.x + bb2.x + bbb.x);
  v.y += w0 * (a.y + a2.y + ba.y) + w1 * (bb1.y + bb2.y + bbb.y);
  v.z += w0 * (a.z + a2.z + ba.z) + w1 * (bb1.z + bb2.z + bbb.z);
  v.w += w0 * (a.w + a2.w + ba.w) + w1 * (bb1.w + bb2.w + bbb.w);
  __shared__ float sm1[4], sm2[4];
  float s = v.x + v.y + v.z + v.w;
  for (int o = 32; o > 0; o >>= 1) s += __shfl_down(s, o);
  if ((tid & 63) == 0) sm1[tid >> 6] = s;
  __syncthreads();
  float mean = (sm1[0] + sm1[1] + sm1[2] + sm1[3]) * (1.0f / DM);
  float d0 = v.x - mean, d1 = v.y - mean, d2 = v.z - mean, d3 = v.w - mean;
  float q = d0 * d0 + d1 * d1 + d2 * d2 + d3 * d3;
  for (int o = 32; o > 0; o >>= 1) q += __shfl_down(q, o);
  if ((tid & 63) == 0) sm2[tid >> 6] = q;
  __syncthreads();
  float var = (sm2[0] + sm2[1] + sm2[2] + sm2[3]) * (1.0f / DM);
  float rstd = rsqrtf(var + 1e-5f);
  float4 gv = ((const float4*)g)[tid];
  float4 bv = ((const float4*)b)[tid];
  long long base = (long long)tok * DM + tid * 4;
  outH[base + 0] = f2b(d0 * rstd * gv.x + bv.x);
  outH[base + 1] = f2b(d1 * rstd * gv.y + bv.y);
  outH[base + 2] = f2b(d2 * rstd * gv.z + bv.z);
  outH[base + 3] = f2b(d3 * rstd * gv.w + bv.w);
}

extern "C" void kernel_launch(void* const* d_in, const int* in_sizes, int n_in,
                              void* d_out, int out_size, void* d_ws, size_t ws_size,
                              hipStream_t stream)
{
  const int* ids = (const int*)d_in[0];
  const float* embed_w = (const float*)d_in[1];
  const float* pos_w   = (const float*)d_in[2];
  const float* ln1_g[2] = {(const float*)d_in[3],  (const float*)d_in[11]};
  const float* ln1_b[2] = {(const float*)d_in[4],  (const float*)d_in[12]};
  const float* in_w[2]  = {(const float*)d_in[5],  (const float*)d_in[13]};
  const float* in_b[2]  = {(const float*)d_in[6],  (const float*)d_in[14]};
  const float* out_w[2] = {(const float*)d_in[7],  (const float*)d_in[15]};
  const float* out_b[2] = {(const float*)d_in[8],  (const float*)d_in[16]};
  const float* ln2_g[2] = {(const float*)d_in[9],  (const float*)d_in[17]};
  const float* ln2_b[2] = {(const float*)d_in[10], (const float*)d_in[18]};
  const float* ffn_w1 = (const float*)d_in[19];
  const float* ffn_b1 = (const float*)d_in[20];
  const float* ffn_w2 = (const float*)d_in[21];
  const float* ffn_b2 = (const float*)d_in[22];
  const float* gate_w = (const float*)d_in[23];
  const float* gate_b = (const float*)d_in[24];
  const float* moe_w1 = (const float*)d_in[25];
  const float* moe_b1 = (const float*)d_in[26];
  const float* moe_w2 = (const float*)d_in[27];
  const float* moe_b2 = (const float*)d_in[28];
  const float* norm_g = (const float*)d_in[29];
  const float* norm_b = (const float*)d_in[30];
  const float* head_w = (const float*)d_in[31];

  char* ob = (char*)d_out;
  size_t off = 0;
  auto alloc = [&](size_t bytes) {
    char* p = ob + off;
    off = (off + bytes + 255) & ~(size_t)255;
    return p;
  };
  float*    x      = (float*)alloc((size_t)SQ * DM * 4);
  ushort_t* hbufH  = (ushort_t*)alloc((size_t)SQ * DM * 2);
  ushort_t* hbufL  = (ushort_t*)alloc((size_t)SQ * DM * 2);
  ushort_t* qkvH   = (ushort_t*)alloc((size_t)SQ * 3 * DM * 2);   // ┐
  ushort_t* qkvL   = (ushort_t*)alloc((size_t)SQ * 3 * DM * 2);   // │ w2b
  ushort_t* VtH    = (ushort_t*)alloc((size_t)NH * HDIM * SQ * 2);// │ 64MiB
  ushort_t* VtL    = (ushort_t*)alloc((size_t)NH * HDIM * SQ * 2);// │
  char*     resv   = (char*)alloc((size_t)32 << 20);              // ┘ filler
  ushort_t* attnH  = (ushort_t*)alloc((size_t)SQ * DM * 2);
  ushort_t* attnL  = (ushort_t*)alloc((size_t)SQ * DM * 2);
  ushort_t* Xg     = (ushort_t*)alloc((size_t)2 * SQ * DM * 2);
  int*      topi   = (int*)alloc(SQ * 2 * 4);
  float*    topw   = (float*)alloc(SQ * 2 * 4);
  int*      tokIdx = (int*)alloc(2 * SQ * 4);
  float*    tokW   = (float*)alloc(2 * SQ * 4);
  int*      slotOf = (int*)alloc(2 * SQ * 4);
  int*      counts = (int*)alloc(256);
  int*      offsb  = (int*)alloc(256);
  int*      cursors= (int*)alloc(256);
  ushort_t* ffnH   = (ushort_t*)alloc((size_t)SQ * FFD * 2);      // ┐ moehid
  ushort_t* ffnL   = (ushort_t*)alloc((size_t)SQ * FFD * 2);      // ┘ 32MiB
  float*    eo     = (float*)alloc((size_t)2 * 2 * SQ * DM * 4);  // 32MiB (also KS partials)
  ushort_t* inwH[2], *inwL[2], *outwH[2], *outwL[2];
  ushort_t* wsplit0 = (ushort_t*)alloc(0);
  inwH[0]  = (ushort_t*)alloc((size_t)3 * DM * DM * 2);
  inwL[0]  = (ushort_t*)alloc((size_t)3 * DM * DM * 2);
  inwH[1]  = (ushort_t*)alloc((size_t)3 * DM * DM * 2);
  inwL[1]  = (ushort_t*)alloc((size_t)3 * DM * DM * 2);
  outwH[0] = (ushort_t*)alloc((size_t)DM * DM * 2);
  outwL[0] = (ushort_t*)alloc((size_t)DM * DM * 2);
  outwH[1] = (ushort_t*)alloc((size_t)DM * DM * 2);
  outwL[1] = (ushort_t*)alloc((size_t)DM * DM * 2);
  ushort_t* f1H = (ushort_t*)alloc((size_t)FFD * DM * 2);
  ushort_t* f1L = (ushort_t*)alloc((size_t)FFD * DM * 2);
  ushort_t* f2H = (ushort_t*)alloc((size_t)DM * FFD * 2);
  ushort_t* f2L = (ushort_t*)alloc((size_t)DM * FFD * 2);
  ushort_t* moe_w1b = wsplit0;            // 64 MiB over weight planes
  ushort_t* moe_w2b = qkvH;               // 64 MiB over qkv+Vt+resv
  ushort_t* moehid  = ffnH;               // 32 MiB over ffn planes
  float*    pp      = eo;                 // KS partial planes
  const long long eoPC = (long long)2 * SQ * DM;
  const long long ppPC = (long long)SQ * DM;
  ushort_t* hfin    = (ushort_t*)d_ws;
  bool wsBig = ws_size >= ((size_t)70 << 20);
  ushort_t* head_wb = (ushort_t*)((char*)d_ws + ((size_t)4 << 20));
  (void)resv;

  embed_kernel<<<SQ, 256, 0, stream>>>(ids, embed_w, pos_w, x, counts);
  cvt_split2<<<dim3(512, 2), 256, 0, stream>>>(
      in_w[0], inwH[0], inwL[0], in_w[1], inwH[1], inwL[1], 3 * DM * DM / 4);
  cvt_split2<<<dim3(512, 2), 256, 0, stream>>>(
      out_w[0], outwH[0], outwL[0], out_w[1], outwH[1], outwL[1], DM * DM / 4);
  cvt_split2<<<dim3(512, 2), 256, 0, stream>>>(
      ffn_w1, f1H, f1L, ffn_w2, f2H, f2L, FFD * DM / 4);
  if (wsBig)
    cvt_bf16<<<1024, 256, 0, stream>>>(head_w, head_wb, NVOC * DM / 4);

  // ---- Layer 0 ----
  ln_fused<0, 0><<<SQ, 256, 0, stream>>>(x, nullptr, 0, nullptr,
                                         ln1_g[0], ln1_b[0], hbufH, hbufL);
  k_qkv<<<dim3(16, 24, 1), 256, 0, stream>>>(
      hbufH, hbufL, DM, 0, inwH[0], inwL[0], DM, 0,
      nullptr, qkvH, qkvL, 3 * DM, 0, 0,
      SQ, 3 * DM, DM, in_b[0], 1.f, VtH, VtL);
  k_attn<<<dim3(SQ / 64, NH), 256, 0, stream>>>(qkvH, qkvL, VtH, VtL,
                                                attnH, attnL);
  k_outp<<<dim3(16, 16, 4), 256, 0, stream>>>(
      attnH, attnL, DM, 0, outwH[0], outwL[0], DM, 0,
      pp, nullptr, nullptr, DM, 0, ppPC,
      SQ, DM, DM / 4, nullptr, 1.f, nullptr, nullptr);
  ln_fused<0, 4><<<SQ, 256, 0, stream>>>(x, pp, ppPC, out_b[0],
                                         ln2_g[0], ln2_b[0], hbufH, hbufL);
  k_ffn1<<<dim3(16, 32, 1), 256, 0, stream>>>(
      hbufH, hbufL, DM, 0, f1H, f1L, DM, 0,
      nullptr, ffnH, ffnL, FFD, 0, 0,
      SQ, FFD, DM, ffn_b1, 1.f, nullptr, nullptr);
  k_ffn2<<<dim3(16, 16, 2), 256, 0, stream>>>(
      ffnH, ffnL, FFD, 0, f2H, f2L, FFD, 0,
      pp, nullptr, nullptr, DM, 0, ppPC,
      SQ, DM, FFD / 2, nullptr, 1.f, nullptr, nullptr);
  // ---- Layer 1 ----
  ln_fused<0, 2><<<SQ, 256, 0, stream>>>(x, pp, ppPC, ffn_b2,
                                         ln1_g[1], ln1_b[1], hbufH, hbufL);
  k_qkv<<<dim3(16, 24, 1), 256, 0, stream>>>(
      hbufH, hbufL, DM, 0, inwH[1], inwL[1], DM, 0,
      nullptr, qkvH, qkvL, 3 * DM, 0, 0,
      SQ, 3 * DM, DM, in_b[1], 1.f, VtH, VtL);
  k_attn<<<dim3(SQ / 64, NH), 256, 0, stream>>>(qkvH, qkvL, VtH, VtL,
                                                attnH, attnL);
  k_outp<<<dim3(16, 16, 4), 256, 0, stream>>>(
      attnH, attnL, DM, 0, outwH[1], outwL[1], DM, 0,
      pp, nullptr, nullptr, DM, 0, ppPC,
      SQ, DM, DM / 4, nullptr, 1.f, nullptr, nullptr);
  cvt_bf16_2<<<dim3(2048, 2), 256, 0, stream>>>(
      moe_w1, moe_w1b, moe_w2, moe_w2b, 8 * FFD * DM / 4);
  ln_gate_top2<<<SQ, 256, 0, stream>>>(x, pp, ppPC, out_b[1],
                                       ln2_g[1], ln2_b[1], gate_w, gate_b,
                                       topi, topw, counts, hbufH);
  moe_prefix<<<1, 64, 0, stream>>>(counts, offsb, cursors);
  moe_gather<<<SQ, 256, 0, stream>>>(hbufH, topi, topw, offsb, cursors,
                                     tokIdx, tokW, slotOf, Xg);
  k_moe1<<<dim3(32, 16, 8), 256, 0, stream>>>(
      Xg, DM, 0, moe_w1b, DM, (long long)FFD * DM,
      moehid, FFD, 0, 0, SQ, FFD, DM, moe_b1, FFD, offsb);
  k_moe2<<<dim3(8, 16, 16), 256, 0, stream>>>(
      moehid, FFD, 0, moe_w2b, FFD, (long long)DM * FFD,
      eo, DM, 0, eoPC, SQ, DM, FFD, nullptr, 0, offsb);
  moe_ln_final<<<SQ, 256, 0, stream>>>(x, eo, eoPC, slotOf, topi, topw,
                                       moe_b2, norm_g, norm_b, hfin);
  if (wsBig)
    k_head_bf<<<dim3(8, 250, 1), 256, 0, stream>>>(
        hfin, DM, 0, head_wb, DM, 0, d_out, NVOC, 0, 0,
        SQ, NVOC, DM, nullptr, 0, nullptr);
  else
    k_head_f<<<dim3(8, 250, 1), 256, 0, stream>>>(
        hfin, DM, 0, head_w, DM, 0, d_out, NVOC, 0, 0,
        SQ, NVOC, DM, nullptr, 0, nullptr);
}